// Round 1
// baseline (2069.058 us; speedup 1.0000x reference)
//
#include <hip/hip_runtime.h>
#include <cstddef>

#define T_SEQ 1024
#define D_MODEL 512

// =====================================================================
// GEMM: C[8192x512] = A[8192x512] @ W[512x512] (+ bias) (+= C if accumulate)
// BM=128 BN=128 BK=16, 256 threads, 8x8 micro-tile per thread.
// =====================================================================
__global__ __launch_bounds__(256)
void gemm_kernel(const float* __restrict__ A, const float* __restrict__ W,
                 const float* __restrict__ bias, float* __restrict__ C,
                 int accumulate) {
  constexpr int BM = 128, BN = 128, BK = 16;
  constexpr int K = 512, N = 512;
  __shared__ float As[BK][132];   // transposed A tile, padded vs bank conflicts
  __shared__ float Bs[BK][132];
  const int tid = threadIdx.x;
  const int tx = tid & 15, ty = tid >> 4;
  const int row0 = blockIdx.y * BM, col0 = blockIdx.x * BN;

  float acc[8][8];
#pragma unroll
  for (int i = 0; i < 8; ++i)
#pragma unroll
    for (int j = 0; j < 8; ++j) acc[i][j] = 0.f;

  for (int k0 = 0; k0 < K; k0 += BK) {
    __syncthreads();
#pragma unroll
    for (int it = 0; it < 2; ++it) {          // A: 128x16, store transposed
      const int idx = tid + it * 256;
      const int r = idx >> 2, c4 = (idx & 3) << 2;
      const float4 v = *(const float4*)(A + (size_t)(row0 + r) * K + k0 + c4);
      As[c4 + 0][r] = v.x; As[c4 + 1][r] = v.y;
      As[c4 + 2][r] = v.z; As[c4 + 3][r] = v.w;
    }
#pragma unroll
    for (int it = 0; it < 2; ++it) {          // B: 16x128
      const int idx = tid + it * 256;
      const int r = idx >> 5, c4 = (idx & 31) << 2;
      *(float4*)&Bs[r][c4] = *(const float4*)(W + (size_t)(k0 + r) * N + col0 + c4);
    }
    __syncthreads();
#pragma unroll
    for (int kk = 0; kk < BK; ++kk) {
      float a[8], b[8];
      *(float4*)&a[0] = *(float4*)&As[kk][ty * 8];
      *(float4*)&a[4] = *(float4*)&As[kk][ty * 8 + 4];
      *(float4*)&b[0] = *(float4*)&Bs[kk][tx * 8];
      *(float4*)&b[4] = *(float4*)&Bs[kk][tx * 8 + 4];
#pragma unroll
      for (int i = 0; i < 8; ++i)
#pragma unroll
        for (int j = 0; j < 8; ++j)
          acc[i][j] = fmaf(a[i], b[j], acc[i][j]);
    }
  }

  const int col = col0 + tx * 8;
  float bv[8];
  if (bias) {
    const float4 b0 = *(const float4*)(bias + col);
    const float4 b1 = *(const float4*)(bias + col + 4);
    bv[0] = b0.x; bv[1] = b0.y; bv[2] = b0.z; bv[3] = b0.w;
    bv[4] = b1.x; bv[5] = b1.y; bv[6] = b1.z; bv[7] = b1.w;
  } else {
#pragma unroll
    for (int j = 0; j < 8; ++j) bv[j] = 0.f;
  }
#pragma unroll
  for (int i = 0; i < 8; ++i) {
    float* cp = C + (size_t)(row0 + ty * 8 + i) * N + col;
    float o[8];
#pragma unroll
    for (int j = 0; j < 8; ++j) o[j] = acc[i][j] + bv[j];
    if (accumulate) {
      const float4 c0 = *(const float4*)cp;
      const float4 c1 = *((const float4*)cp + 1);
      o[0] += c0.x; o[1] += c0.y; o[2] += c0.z; o[3] += c0.w;
      o[4] += c1.x; o[5] += c1.y; o[6] += c1.z; o[7] += c1.w;
    }
    *(float4*)cp       = make_float4(o[0], o[1], o[2], o[3]);
    *((float4*)cp + 1) = make_float4(o[4], o[5], o[6], o[7]);
  }
}

// =====================================================================
// Local windowed attention, one wave per (b,t).
// Head split is the ROW-MAJOR reshape: m = j*8+c = h*W+p.
// Out-of-range rows == the bias vector (padded x row is zero).
// Output: abar[bt][d] = mean_j att[bt][j][d]   (output proj applied later)
// =====================================================================
template <int W>
__global__ __launch_bounds__(256)
void local_attn_kernel(const float* __restrict__ Xq, const float* __restrict__ Xk,
                       const float* __restrict__ Xv,
                       const float* __restrict__ bq, const float* __restrict__ bk,
                       const float* __restrict__ bv,
                       float* __restrict__ abar) {
  constexpr int PAD = (W - 1) / 2;
  __shared__ float att_lds[4][8 * W][68];
  const int wave = threadIdx.x >> 6;
  const int lane = threadIdx.x & 63;
  const int bt = (blockIdx.x << 2) + wave;
  const int b = bt >> 10, t = bt & 1023;
  const int h = lane >> 3;
  const int colb = (lane & 7) * 8;

  // q fragments: q[p][e] = Q[head h, seq p, feat colb+e]
  float q[W][8];
#pragma unroll
  for (int p = 0; p < W; ++p) {
    const int m = h * W + p, j = m >> 3, c = m & 7;
    const int s = t + j - PAD;
    const float* src = (s >= 0 && s < T_SEQ)
                           ? Xq + ((size_t)(b * T_SEQ + s) << 9) + c * 64 + colb
                           : bq + c * 64 + colb;
    const float4 v0 = *(const float4*)src, v1 = *(const float4*)(src + 4);
    q[p][0] = v0.x; q[p][1] = v0.y; q[p][2] = v0.z; q[p][3] = v0.w;
    q[p][4] = v1.x; q[p][5] = v1.y; q[p][6] = v1.z; q[p][7] = v1.w;
  }

  // scores (full dot via 8-lane shuffle reduce; replicated across the group)
  float sc[W][W];
#pragma unroll
  for (int pk = 0; pk < W; ++pk) {
    const int m = h * W + pk, j = m >> 3, c = m & 7;
    const int s = t + j - PAD;
    const float* src = (s >= 0 && s < T_SEQ)
                           ? Xk + ((size_t)(b * T_SEQ + s) << 9) + c * 64 + colb
                           : bk + c * 64 + colb;
    const float4 v0 = *(const float4*)src, v1 = *(const float4*)(src + 4);
    const float kr[8] = {v0.x, v0.y, v0.z, v0.w, v1.x, v1.y, v1.z, v1.w};
#pragma unroll
    for (int pq = 0; pq < W; ++pq) {
      float d = 0.f;
#pragma unroll
      for (int e = 0; e < 8; ++e) d = fmaf(q[pq][e], kr[e], d);
      d += __shfl_xor(d, 1);
      d += __shfl_xor(d, 2);
      d += __shfl_xor(d, 4);
      sc[pq][pk] = d * 0.125f;   // / sqrt(64)
    }
  }

  // softmax rows, in place
#pragma unroll
  for (int pq = 0; pq < W; ++pq) {
    float mx = sc[pq][0];
#pragma unroll
    for (int pk = 1; pk < W; ++pk) mx = fmaxf(mx, sc[pq][pk]);
    float sum = 0.f;
#pragma unroll
    for (int pk = 0; pk < W; ++pk) {
      const float e = __expf(sc[pq][pk] - mx);
      sc[pq][pk] = e;
      sum += e;
    }
    const float inv = 1.f / sum;
#pragma unroll
    for (int pk = 0; pk < W; ++pk) sc[pq][pk] *= inv;
  }

  // att = P @ V
  float av[W][8];
#pragma unroll
  for (int p = 0; p < W; ++p)
#pragma unroll
    for (int e = 0; e < 8; ++e) av[p][e] = 0.f;
#pragma unroll
  for (int pk = 0; pk < W; ++pk) {
    const int m = h * W + pk, j = m >> 3, c = m & 7;
    const int s = t + j - PAD;
    const float* src = (s >= 0 && s < T_SEQ)
                           ? Xv + ((size_t)(b * T_SEQ + s) << 9) + c * 64 + colb
                           : bv + c * 64 + colb;
    const float4 v0 = *(const float4*)src, v1 = *(const float4*)(src + 4);
    const float vr[8] = {v0.x, v0.y, v0.z, v0.w, v1.x, v1.y, v1.z, v1.w};
#pragma unroll
    for (int pq = 0; pq < W; ++pq)
#pragma unroll
      for (int e = 0; e < 8; ++e) av[pq][e] = fmaf(sc[pq][pk], vr[e], av[pq][e]);
  }

  // stage att (indexed by m = j*8+c) in LDS, then average over j
#pragma unroll
  for (int p = 0; p < W; ++p) {
    const int m = h * W + p;
    *(float4*)&att_lds[wave][m][colb] =
        make_float4(av[p][0], av[p][1], av[p][2], av[p][3]);
    *(float4*)&att_lds[wave][m][colb + 4] =
        make_float4(av[p][4], av[p][5], av[p][6], av[p][7]);
  }
  __syncthreads();
  const int cc = lane >> 3, fb = (lane & 7) * 8;
  float o[8] = {0.f, 0.f, 0.f, 0.f, 0.f, 0.f, 0.f, 0.f};
#pragma unroll
  for (int j = 0; j < W; ++j) {
    const float* sp = &att_lds[wave][j * 8 + cc][fb];
    const float4 a0 = *(const float4*)sp, a1 = *(const float4*)(sp + 4);
    o[0] += a0.x; o[1] += a0.y; o[2] += a0.z; o[3] += a0.w;
    o[4] += a1.x; o[5] += a1.y; o[6] += a1.z; o[7] += a1.w;
  }
  const float invw = 1.f / (float)W;
  float* dst = abar + ((size_t)bt << 9) + lane * 8;
  *(float4*)dst       = make_float4(o[0] * invw, o[1] * invw, o[2] * invw, o[3] * invw);
  *((float4*)dst + 1) = make_float4(o[4] * invw, o[5] * invw, o[6] * invw, o[7] * invw);
}

// =====================================================================
// Global attention. Head = t/128 (row-major reshape!), seq r = (t%128)*8+c.
// 64 (b,head) batches of S=1024, dh=64. Flash-style online softmax.
// Block: one (b,head, 64-row q-tile); 256 threads; thread=(qi, u): 16 scores
// + 16 output features. Writes result back in [b,t,d] layout to `att`.
// =====================================================================
__global__ __launch_bounds__(256)
void global_attn_kernel(const float* __restrict__ Xq, const float* __restrict__ Xk,
                        const float* __restrict__ Xv, float* __restrict__ att) {
  __shared__ float Qs[64][68];
  __shared__ float Ks[64][68];
  __shared__ float Vs[64][68];
  __shared__ float Ps[64][68];
  const int tid = threadIdx.x;
  const int qt = blockIdx.x;        // 0..15
  const int bh = blockIdx.y;        // 0..63
  const int b = bh >> 3, hp = bh & 7;
  const size_t base = (size_t)b * T_SEQ * D_MODEL;

  // load Q tile (pre-scaled by 1/8)
#pragma unroll
  for (int it = 0; it < 4; ++it) {
    const int idx = tid + it * 256;
    const int row = idx >> 4, c4 = (idx & 15) << 2;
    const int r = qt * 64 + row;
    const int tt = hp * 128 + (r >> 3), cc = r & 7;
    const float4 v = *(const float4*)(Xq + base + (size_t)tt * D_MODEL + cc * 64 + c4);
    Qs[row][c4 + 0] = v.x * 0.125f; Qs[row][c4 + 1] = v.y * 0.125f;
    Qs[row][c4 + 2] = v.z * 0.125f; Qs[row][c4 + 3] = v.w * 0.125f;
  }

  const int qi = tid >> 2, u = tid & 3;
  float O[16];
#pragma unroll
  for (int f = 0; f < 16; ++f) O[f] = 0.f;
  float m_run = -1e30f, l_run = 0.f;

  for (int kt = 0; kt < 16; ++kt) {
    __syncthreads();
#pragma unroll
    for (int it = 0; it < 4; ++it) {
      const int idx = tid + it * 256;
      const int row = idx >> 4, c4 = (idx & 15) << 2;
      const int kr = kt * 64 + row;
      const int tt = hp * 128 + (kr >> 3), cc = kr & 7;
      *(float4*)&Ks[row][c4] = *(const float4*)(Xk + base + (size_t)tt * D_MODEL + cc * 64 + c4);
      *(float4*)&Vs[row][c4] = *(const float4*)(Xv + base + (size_t)tt * D_MODEL + cc * 64 + c4);
    }
    __syncthreads();

    float s[16];
#pragma unroll
    for (int kk = 0; kk < 16; ++kk) s[kk] = 0.f;
    for (int d0 = 0; d0 < 64; d0 += 4) {
      const float4 q4 = *(const float4*)&Qs[qi][d0];
#pragma unroll
      for (int kk = 0; kk < 16; ++kk) {
        const float4 k4 = *(const float4*)&Ks[u * 16 + kk][d0];
        s[kk] = fmaf(q4.x, k4.x, fmaf(q4.y, k4.y, fmaf(q4.z, k4.z, fmaf(q4.w, k4.w, s[kk]))));
      }
    }

    float mt = s[0];
#pragma unroll
    for (int kk = 1; kk < 16; ++kk) mt = fmaxf(mt, s[kk]);
    mt = fmaxf(mt, __shfl_xor(mt, 1));
    mt = fmaxf(mt, __shfl_xor(mt, 2));
    const float m_new = fmaxf(m_run, mt);
    const float alpha = __expf(m_run - m_new);
    float lsum = 0.f;
#pragma unroll
    for (int kk = 0; kk < 16; ++kk) {
      const float e = __expf(s[kk] - m_new);
      Ps[qi][u * 16 + kk] = e;
      lsum += e;
    }
    lsum += __shfl_xor(lsum, 1);
    lsum += __shfl_xor(lsum, 2);
    l_run = l_run * alpha + lsum;
    m_run = m_new;
#pragma unroll
    for (int f = 0; f < 16; ++f) O[f] *= alpha;
    __syncthreads();

    for (int k0 = 0; k0 < 64; k0 += 16) {
      float p[16];
      *(float4*)&p[0]  = *(const float4*)&Ps[qi][k0];
      *(float4*)&p[4]  = *(const float4*)&Ps[qi][k0 + 4];
      *(float4*)&p[8]  = *(const float4*)&Ps[qi][k0 + 8];
      *(float4*)&p[12] = *(const float4*)&Ps[qi][k0 + 12];
#pragma unroll
      for (int kk = 0; kk < 16; ++kk) {
        const float* vr = &Vs[k0 + kk][u * 16];
        const float4 v0 = *(const float4*)vr;
        const float4 v1 = *(const float4*)(vr + 4);
        const float4 v2 = *(const float4*)(vr + 8);
        const float4 v3 = *(const float4*)(vr + 12);
        O[0]  = fmaf(p[kk], v0.x, O[0]);  O[1]  = fmaf(p[kk], v0.y, O[1]);
        O[2]  = fmaf(p[kk], v0.z, O[2]);  O[3]  = fmaf(p[kk], v0.w, O[3]);
        O[4]  = fmaf(p[kk], v1.x, O[4]);  O[5]  = fmaf(p[kk], v1.y, O[5]);
        O[6]  = fmaf(p[kk], v1.z, O[6]);  O[7]  = fmaf(p[kk], v1.w, O[7]);
        O[8]  = fmaf(p[kk], v2.x, O[8]);  O[9]  = fmaf(p[kk], v2.y, O[9]);
        O[10] = fmaf(p[kk], v2.z, O[10]); O[11] = fmaf(p[kk], v2.w, O[11]);
        O[12] = fmaf(p[kk], v3.x, O[12]); O[13] = fmaf(p[kk], v3.y, O[13]);
        O[14] = fmaf(p[kk], v3.z, O[14]); O[15] = fmaf(p[kk], v3.w, O[15]);
      }
    }
  }

  const float invl = 1.f / l_run;
  const int r = qt * 64 + qi;
  const int tt = hp * 128 + (r >> 3), cc = r & 7;
  float* dst = att + base + (size_t)tt * D_MODEL + cc * 64 + u * 16;
#pragma unroll
  for (int f0 = 0; f0 < 16; f0 += 4)
    *(float4*)(dst + f0) =
        make_float4(O[f0] * invl, O[f0 + 1] * invl, O[f0 + 2] * invl, O[f0 + 3] * invl);
}

// =====================================================================
// Launch
// =====================================================================
extern "C" void kernel_launch(void* const* d_in, const int* in_sizes, int n_in,
                              void* d_out, int out_size, void* d_ws, size_t ws_size,
                              hipStream_t stream) {
  const float* x      = (const float*)d_in[0];
  const float* loc_wq = (const float*)d_in[1];
  const float* loc_bq = (const float*)d_in[2];
  const float* loc_wk = (const float*)d_in[3];
  const float* loc_bk = (const float*)d_in[4];
  const float* loc_wv = (const float*)d_in[5];
  const float* loc_bv = (const float*)d_in[6];
  const float* loc_wo = (const float*)d_in[7];
  const float* loc_bo = (const float*)d_in[8];
  const float* g_wq  = (const float*)d_in[9];
  const float* g_bq  = (const float*)d_in[10];
  const float* g_wk  = (const float*)d_in[11];
  const float* g_bk  = (const float*)d_in[12];
  const float* g_wv  = (const float*)d_in[13];
  const float* g_bv  = (const float*)d_in[14];
  const float* g_wo  = (const float*)d_in[15];
  const float* g_bo  = (const float*)d_in[16];
  const float* out_w = (const float*)d_in[17];
  const float* out_b = (const float*)d_in[18];
  float* out = (float*)d_out;

  float* ws = (float*)d_ws;
  const size_t SZ = (size_t)8192 * 512;
  float* Xq    = ws;
  float* Xk    = ws + SZ;
  float* Xv    = ws + 2 * SZ;
  float* abar  = ws + 3 * SZ;
  float* feats = ws + 4 * SZ;

  const dim3 ggrid(4, 64);   // N/128, M/128
  const dim3 thr(256);

  for (int lv = 0; lv < 3; ++lv) {
    const size_t wo_off = (size_t)lv * 512 * 512;
    const float* wq = loc_wq + wo_off; const float* bqv = loc_bq + lv * 512;
    const float* wk = loc_wk + wo_off; const float* bkv = loc_bk + lv * 512;
    const float* wv = loc_wv + wo_off; const float* bvv = loc_bv + lv * 512;
    const float* wo = loc_wo + wo_off; const float* bov = loc_bo + lv * 512;

    gemm_kernel<<<ggrid, thr, 0, stream>>>(x, wq, bqv, Xq, 0);
    gemm_kernel<<<ggrid, thr, 0, stream>>>(x, wk, bkv, Xk, 0);
    gemm_kernel<<<ggrid, thr, 0, stream>>>(x, wv, bvv, Xv, 0);

    if (lv == 0)
      local_attn_kernel<3><<<2048, thr, 0, stream>>>(Xq, Xk, Xv, bqv, bkv, bvv, abar);
    else if (lv == 1)
      local_attn_kernel<5><<<2048, thr, 0, stream>>>(Xq, Xk, Xv, bqv, bkv, bvv, abar);
    else
      local_attn_kernel<7><<<2048, thr, 0, stream>>>(Xq, Xk, Xv, bqv, bkv, bvv, abar);

    gemm_kernel<<<ggrid, thr, 0, stream>>>(abar, wo, bov, feats, 0);
    // out (+)= feats @ out_w[rows lv*512 .. lv*512+512]; part 0 initializes + out_b
    gemm_kernel<<<ggrid, thr, 0, stream>>>(feats, out_w + (size_t)lv * 512 * 512,
                                           lv == 0 ? out_b : nullptr, out, lv == 0 ? 0 : 1);
  }

  // global branch
  gemm_kernel<<<ggrid, thr, 0, stream>>>(x, g_wq, g_bq, Xq, 0);
  gemm_kernel<<<ggrid, thr, 0, stream>>>(x, g_wk, g_bk, Xk, 0);
  gemm_kernel<<<ggrid, thr, 0, stream>>>(x, g_wv, g_bv, Xv, 0);
  global_attn_kernel<<<dim3(16, 64), thr, 0, stream>>>(Xq, Xk, Xv, abar);
  gemm_kernel<<<ggrid, thr, 0, stream>>>(abar, g_wo, g_bo, feats, 0);
  gemm_kernel<<<ggrid, thr, 0, stream>>>(feats, out_w + (size_t)3 * 512 * 512,
                                         nullptr, out, 1);
}

// Round 2
// 746.686 us; speedup vs baseline: 2.7710x; 2.7710x over previous
//
#include <hip/hip_runtime.h>
#include <hip/hip_bf16.h>
#include <cstddef>

#define T_SEQ 1024
#define D_MODEL 512

typedef __attribute__((ext_vector_type(8))) __bf16 bf16x8;
typedef __attribute__((ext_vector_type(4))) float f32x4;
typedef __attribute__((ext_vector_type(8))) unsigned short u16x8;

typedef const unsigned int __attribute__((address_space(1)))* gas1_t;
typedef unsigned int __attribute__((address_space(3)))* las3_t;

__device__ __forceinline__ void gload_lds16(const void* g, void* l) {
  __builtin_amdgcn_global_load_lds((gas1_t)g, (las3_t)l, 16, 0, 0);
}

__device__ __forceinline__ float bf2f(unsigned short u) {
  return __uint_as_float(((unsigned)u) << 16);
}
__device__ __forceinline__ unsigned short f2bf(float f) {
  __hip_bfloat16 h = __float2bfloat16(f);
  return *(unsigned short*)&h;
}

// =====================================================================
// Cast x fp32 -> bf16 (each thread 8 elems)
// =====================================================================
__global__ __launch_bounds__(256)
void cast_x_kernel(const float* __restrict__ in, __hip_bfloat16* __restrict__ out) {
  const int i = (blockIdx.x * 256 + threadIdx.x) * 8;
  const float4 a = *(const float4*)(in + i);
  const float4 b = *(const float4*)(in + i + 4);
  u16x8 o;
  o[0] = f2bf(a.x); o[1] = f2bf(a.y); o[2] = f2bf(a.z); o[3] = f2bf(a.w);
  o[4] = f2bf(b.x); o[5] = f2bf(b.y); o[6] = f2bf(b.z); o[7] = f2bf(b.w);
  *(u16x8*)(out + i) = o;
}

// =====================================================================
// Transpose+cast one (or several stacked) 512x512 fp32 matrices to bf16:
// dst[n][k] = src[k][n].  grid.x = 256 (16x16 tiles of 32x32), grid.y = mat.
// =====================================================================
__global__ __launch_bounds__(256)
void transpose_cast_kernel(const float* __restrict__ src, __hip_bfloat16* __restrict__ dst) {
  __shared__ float tile[32][33];
  const float* W = src + (size_t)blockIdx.y * 262144;
  __hip_bfloat16* WT = dst + (size_t)blockIdx.y * 262144;
  const int tk = (blockIdx.x & 15) * 32;
  const int tn = (blockIdx.x >> 4) * 32;
  const int t = threadIdx.x;
  const int r = t >> 3, c4 = (t & 7) * 4;
  const float4 v = *(const float4*)(W + (size_t)(tk + r) * 512 + tn + c4);
  tile[r][c4 + 0] = v.x; tile[r][c4 + 1] = v.y;
  tile[r][c4 + 2] = v.z; tile[r][c4 + 3] = v.w;
  __syncthreads();
  ushort4 o;
  o.x = f2bf(tile[c4 + 0][r]); o.y = f2bf(tile[c4 + 1][r]);
  o.z = f2bf(tile[c4 + 2][r]); o.w = f2bf(tile[c4 + 3][r]);
  *(ushort4*)(WT + (size_t)(tn + r) * 512 + tk + c4) = o;
}

// =====================================================================
// MFMA GEMM core: C[8192x512] = A[8192x512] @ W[512x512], W given as
// WT[n][k] bf16.  Tile BM=64 x BN=128, BK=32, 256 thr = 4 waves (2x2),
// wave tile 32x64 = acc[2][4] 16x16 frags, global_load_lds staging.
// =====================================================================
__device__ __forceinline__ void gemm_core_512(
    const __hip_bfloat16* __restrict__ A, const __hip_bfloat16* __restrict__ BT,
    __hip_bfloat16* As, __hip_bfloat16* Bs, int row0, int col0, f32x4 acc[2][4]) {
  const int tid = threadIdx.x;
  const int wv = tid >> 6, lane = tid & 63;
  const int g = lane >> 4, r16 = lane & 15;
  const int wm = wv >> 1, wn = wv & 1;
#pragma unroll
  for (int m = 0; m < 2; ++m)
#pragma unroll
    for (int n = 0; n < 4; ++n) acc[m][n] = (f32x4)(0.0f);
  const char* Ab = (const char*)A;
  const char* Bb = (const char*)BT;
  for (int k0 = 0; k0 < 512; k0 += 32) {
    // A tile 64x32 bf16 = 4KB (1 round); rows: 64B each
    {
      const int row = tid >> 2, off = (tid & 3) << 4;
      gload_lds16(Ab + (size_t)(row0 + row) * 1024 + k0 * 2 + off,
                  (char*)As + (wv << 10));
    }
    // B tile 128x32 bf16 = 8KB (2 rounds)
    {
      const int row = tid >> 2, off = (tid & 3) << 4;
      gload_lds16(Bb + (size_t)(col0 + row) * 1024 + k0 * 2 + off,
                  (char*)Bs + (wv << 10));
      const int c2 = tid + 256;
      const int row2 = c2 >> 2, off2 = (c2 & 3) << 4;
      gload_lds16(Bb + (size_t)(col0 + row2) * 1024 + k0 * 2 + off2,
                  (char*)Bs + 4096 + (wv << 10));
    }
    __syncthreads();
    bf16x8 a[2], b[4];
#pragma unroll
    for (int m = 0; m < 2; ++m)
      a[m] = *(const bf16x8*)(As + (wm * 32 + m * 16 + r16) * 32 + g * 8);
#pragma unroll
    for (int n = 0; n < 4; ++n)
      b[n] = *(const bf16x8*)(Bs + (wn * 64 + n * 16 + r16) * 32 + g * 8);
#pragma unroll
    for (int m = 0; m < 2; ++m)
#pragma unroll
      for (int n = 0; n < 4; ++n)
        acc[m][n] = __builtin_amdgcn_mfma_f32_16x16x32_bf16(a[m], b[n], acc[m][n], 0, 0, 0);
    __syncthreads();
  }
}

// Fused Q/K/V projection: blockIdx.z selects weight slot / bias / output.
__global__ __launch_bounds__(256, 2)
void gemm_qkv_kernel(const __hip_bfloat16* __restrict__ A,
                     const __hip_bfloat16* __restrict__ WT_base, size_t wt_stride,
                     const float* __restrict__ b0, const float* __restrict__ b1,
                     const float* __restrict__ b2,
                     __hip_bfloat16* __restrict__ out_base) {
  __shared__ __attribute__((aligned(16))) __hip_bfloat16 As[2048];
  __shared__ __attribute__((aligned(16))) __hip_bfloat16 Bs[4096];
  const int z = blockIdx.z;
  const __hip_bfloat16* WT = WT_base + (size_t)z * wt_stride;
  const float* bias = (z == 0) ? b0 : (z == 1) ? b1 : b2;
  __hip_bfloat16* C = out_base + (size_t)z * (size_t)(8192 * 512);
  const int row0 = blockIdx.y * 64, col0 = blockIdx.x * 128;
  f32x4 acc[2][4];
  gemm_core_512(A, WT, As, Bs, row0, col0, acc);
  const int lane = threadIdx.x & 63, wv = threadIdx.x >> 6;
  const int g = lane >> 4, r16 = lane & 15, wm = wv >> 1, wn = wv & 1;
#pragma unroll
  for (int n = 0; n < 4; ++n) {
    const int col = col0 + wn * 64 + n * 16 + r16;
    const float bn = bias[col];
#pragma unroll
    for (int m = 0; m < 2; ++m) {
      const int rowb = row0 + wm * 32 + m * 16 + g * 4;
#pragma unroll
      for (int r = 0; r < 4; ++r)
        C[(size_t)(rowb + r) * 512 + col] = __float2bfloat16(acc[m][n][r] + bn);
    }
  }
}

// Generic single GEMM. mode 0: bf16 out = acc+bias; 1: fp32 out = acc+bias(opt);
// 2: fp32 out += acc.
__global__ __launch_bounds__(256, 2)
void gemm_one_kernel(const __hip_bfloat16* __restrict__ A,
                     const __hip_bfloat16* __restrict__ WT,
                     const float* __restrict__ bias,
                     __hip_bfloat16* __restrict__ Cb, float* __restrict__ Cf,
                     int mode) {
  __shared__ __attribute__((aligned(16))) __hip_bfloat16 As[2048];
  __shared__ __attribute__((aligned(16))) __hip_bfloat16 Bs[4096];
  const int row0 = blockIdx.y * 64, col0 = blockIdx.x * 128;
  f32x4 acc[2][4];
  gemm_core_512(A, WT, As, Bs, row0, col0, acc);
  const int lane = threadIdx.x & 63, wv = threadIdx.x >> 6;
  const int g = lane >> 4, r16 = lane & 15, wm = wv >> 1, wn = wv & 1;
#pragma unroll
  for (int n = 0; n < 4; ++n) {
    const int col = col0 + wn * 64 + n * 16 + r16;
    const float bn = bias ? bias[col] : 0.f;
#pragma unroll
    for (int m = 0; m < 2; ++m) {
      const int rowb = row0 + wm * 32 + m * 16 + g * 4;
#pragma unroll
      for (int r = 0; r < 4; ++r) {
        const size_t idx = (size_t)(rowb + r) * 512 + col;
        if (mode == 0) Cb[idx] = __float2bfloat16(acc[m][n][r] + bn);
        else if (mode == 1) Cf[idx] = acc[m][n][r] + bn;
        else Cf[idx] += acc[m][n][r];
      }
    }
  }
}

// =====================================================================
// Local windowed attention (bf16 in/out), one wave per (b,t).
// Head split m = j*8+c = h*W+p; out-of-range rows == bias (fp32).
// =====================================================================
template <int W>
__global__ __launch_bounds__(256)
void local_attn_kernel(const __hip_bfloat16* __restrict__ Xq,
                       const __hip_bfloat16* __restrict__ Xk,
                       const __hip_bfloat16* __restrict__ Xv,
                       const float* __restrict__ bq, const float* __restrict__ bk,
                       const float* __restrict__ bv,
                       __hip_bfloat16* __restrict__ abar) {
  constexpr int PAD = (W - 1) / 2;
  __shared__ float att_lds[4][8 * W][68];
  const int wave = threadIdx.x >> 6;
  const int lane = threadIdx.x & 63;
  const int bt = (blockIdx.x << 2) + wave;
  const int b = bt >> 10, t = bt & 1023;
  const int h = lane >> 3;
  const int colb = (lane & 7) * 8;

  float q[W][8];
#pragma unroll
  for (int p = 0; p < W; ++p) {
    const int m = h * W + p, j = m >> 3, c = m & 7;
    const int s = t + j - PAD;
    if (s >= 0 && s < T_SEQ) {
      const u16x8 v = *(const u16x8*)(Xq + ((size_t)(b * T_SEQ + s) << 9) + c * 64 + colb);
#pragma unroll
      for (int e = 0; e < 8; ++e) q[p][e] = bf2f(v[e]);
    } else {
      const float* src = bq + c * 64 + colb;
      const float4 v0 = *(const float4*)src, v1 = *(const float4*)(src + 4);
      q[p][0] = v0.x; q[p][1] = v0.y; q[p][2] = v0.z; q[p][3] = v0.w;
      q[p][4] = v1.x; q[p][5] = v1.y; q[p][6] = v1.z; q[p][7] = v1.w;
    }
  }

  float sc[W][W];
#pragma unroll
  for (int pk = 0; pk < W; ++pk) {
    const int m = h * W + pk, j = m >> 3, c = m & 7;
    const int s = t + j - PAD;
    float kr[8];
    if (s >= 0 && s < T_SEQ) {
      const u16x8 v = *(const u16x8*)(Xk + ((size_t)(b * T_SEQ + s) << 9) + c * 64 + colb);
#pragma unroll
      for (int e = 0; e < 8; ++e) kr[e] = bf2f(v[e]);
    } else {
      const float* src = bk + c * 64 + colb;
      const float4 v0 = *(const float4*)src, v1 = *(const float4*)(src + 4);
      kr[0] = v0.x; kr[1] = v0.y; kr[2] = v0.z; kr[3] = v0.w;
      kr[4] = v1.x; kr[5] = v1.y; kr[6] = v1.z; kr[7] = v1.w;
    }
#pragma unroll
    for (int pq = 0; pq < W; ++pq) {
      float d = 0.f;
#pragma unroll
      for (int e = 0; e < 8; ++e) d = fmaf(q[pq][e], kr[e], d);
      d += __shfl_xor(d, 1);
      d += __shfl_xor(d, 2);
      d += __shfl_xor(d, 4);
      sc[pq][pk] = d * 0.125f;
    }
  }

#pragma unroll
  for (int pq = 0; pq < W; ++pq) {
    float mx = sc[pq][0];
#pragma unroll
    for (int pk = 1; pk < W; ++pk) mx = fmaxf(mx, sc[pq][pk]);
    float sum = 0.f;
#pragma unroll
    for (int pk = 0; pk < W; ++pk) {
      const float e = __expf(sc[pq][pk] - mx);
      sc[pq][pk] = e;
      sum += e;
    }
    const float inv = 1.f / sum;
#pragma unroll
    for (int pk = 0; pk < W; ++pk) sc[pq][pk] *= inv;
  }

  float av[W][8];
#pragma unroll
  for (int p = 0; p < W; ++p)
#pragma unroll
    for (int e = 0; e < 8; ++e) av[p][e] = 0.f;
#pragma unroll
  for (int pk = 0; pk < W; ++pk) {
    const int m = h * W + pk, j = m >> 3, c = m & 7;
    const int s = t + j - PAD;
    float vr[8];
    if (s >= 0 && s < T_SEQ) {
      const u16x8 v = *(const u16x8*)(Xv + ((size_t)(b * T_SEQ + s) << 9) + c * 64 + colb);
#pragma unroll
      for (int e = 0; e < 8; ++e) vr[e] = bf2f(v[e]);
    } else {
      const float* src = bv + c * 64 + colb;
      const float4 v0 = *(const float4*)src, v1 = *(const float4*)(src + 4);
      vr[0] = v0.x; vr[1] = v0.y; vr[2] = v0.z; vr[3] = v0.w;
      vr[4] = v1.x; vr[5] = v1.y; vr[6] = v1.z; vr[7] = v1.w;
    }
#pragma unroll
    for (int pq = 0; pq < W; ++pq)
#pragma unroll
      for (int e = 0; e < 8; ++e) av[pq][e] = fmaf(sc[pq][pk], vr[e], av[pq][e]);
  }

#pragma unroll
  for (int p = 0; p < W; ++p) {
    const int m = h * W + p;
    *(float4*)&att_lds[wave][m][colb] =
        make_float4(av[p][0], av[p][1], av[p][2], av[p][3]);
    *(float4*)&att_lds[wave][m][colb + 4] =
        make_float4(av[p][4], av[p][5], av[p][6], av[p][7]);
  }
  __syncthreads();
  const int cc = lane >> 3, fb = (lane & 7) * 8;
  float o[8] = {0.f, 0.f, 0.f, 0.f, 0.f, 0.f, 0.f, 0.f};
#pragma unroll
  for (int j = 0; j < W; ++j) {
    const float* sp = &att_lds[wave][j * 8 + cc][fb];
    const float4 a0 = *(const float4*)sp, a1 = *(const float4*)(sp + 4);
    o[0] += a0.x; o[1] += a0.y; o[2] += a0.z; o[3] += a0.w;
    o[4] += a1.x; o[5] += a1.y; o[6] += a1.z; o[7] += a1.w;
  }
  const float invw = 1.f / (float)W;
  u16x8 ov;
#pragma unroll
  for (int e = 0; e < 8; ++e) ov[e] = f2bf(o[e] * invw);
  *(u16x8*)(abar + ((size_t)bt << 9) + lane * 8) = ov;
}

// =====================================================================
// Global attention (bf16 in/out, fp32 math). The head reshape is a pure
// reshape: Q/K/V rows live at [bh][s][64] contiguous, bh=0..63, s=0..1023.
// Bank-conflict fix: lane u handles kv rows kk*4+u (consecutive rows ->
// banks 4u apart) instead of u*16+kk (16-apart rows -> same bank).
// =====================================================================
__global__ __launch_bounds__(256)
void global_attn_kernel(const __hip_bfloat16* __restrict__ Xq,
                        const __hip_bfloat16* __restrict__ Xk,
                        const __hip_bfloat16* __restrict__ Xv,
                        __hip_bfloat16* __restrict__ att) {
  __shared__ float Qs[64][68];
  __shared__ float Ks[64][68];
  __shared__ float Vs[64][68];
  __shared__ float Ps[64][68];
  const int tid = threadIdx.x;
  const int qt = blockIdx.x;   // 0..15
  const int bh = blockIdx.y;   // 0..63
  const size_t base = (size_t)bh << 16;  // bh * 1024 * 64

#pragma unroll
  for (int it = 0; it < 2; ++it) {
    const int idx = tid + it * 256;
    const int row = idx >> 3, c8 = (idx & 7) * 8;
    const u16x8 v = *(const u16x8*)(Xq + base + (size_t)(qt * 64 + row) * 64 + c8);
#pragma unroll
    for (int e = 0; e < 8; ++e) Qs[row][c8 + e] = bf2f(v[e]) * 0.125f;
  }

  const int qi = tid >> 2, u = tid & 3;
  float O[16];
#pragma unroll
  for (int f = 0; f < 16; ++f) O[f] = 0.f;
  float m_run = -1e30f, l_run = 0.f;

  for (int kt = 0; kt < 16; ++kt) {
    __syncthreads();
#pragma unroll
    for (int it = 0; it < 2; ++it) {
      const int idx = tid + it * 256;
      const int row = idx >> 3, c8 = (idx & 7) * 8;
      const u16x8 kv = *(const u16x8*)(Xk + base + (size_t)(kt * 64 + row) * 64 + c8);
      const u16x8 vv = *(const u16x8*)(Xv + base + (size_t)(kt * 64 + row) * 64 + c8);
#pragma unroll
      for (int e = 0; e < 8; ++e) {
        Ks[row][c8 + e] = bf2f(kv[e]);
        Vs[row][c8 + e] = bf2f(vv[e]);
      }
    }
    __syncthreads();

    float s[16];
#pragma unroll
    for (int kk = 0; kk < 16; ++kk) s[kk] = 0.f;
    for (int d0 = 0; d0 < 64; d0 += 4) {
      const float4 q4 = *(const float4*)&Qs[qi][d0];
#pragma unroll
      for (int kk = 0; kk < 16; ++kk) {
        const float4 k4 = *(const float4*)&Ks[kk * 4 + u][d0];
        s[kk] = fmaf(q4.x, k4.x, fmaf(q4.y, k4.y, fmaf(q4.z, k4.z, fmaf(q4.w, k4.w, s[kk]))));
      }
    }

    float mt = s[0];
#pragma unroll
    for (int kk = 1; kk < 16; ++kk) mt = fmaxf(mt, s[kk]);
    mt = fmaxf(mt, __shfl_xor(mt, 1));
    mt = fmaxf(mt, __shfl_xor(mt, 2));
    const float m_new = fmaxf(m_run, mt);
    const float alpha = __expf(m_run - m_new);
    float lsum = 0.f;
#pragma unroll
    for (int kk = 0; kk < 16; ++kk) {
      const float e = __expf(s[kk] - m_new);
      Ps[qi][kk * 4 + u] = e;
      lsum += e;
    }
    lsum += __shfl_xor(lsum, 1);
    lsum += __shfl_xor(lsum, 2);
    l_run = l_run * alpha + lsum;
    m_run = m_new;
#pragma unroll
    for (int f = 0; f < 16; ++f) O[f] *= alpha;
    __syncthreads();

    for (int k0 = 0; k0 < 64; k0 += 16) {
      float p[16];
      *(float4*)&p[0]  = *(const float4*)&Ps[qi][k0];
      *(float4*)&p[4]  = *(const float4*)&Ps[qi][k0 + 4];
      *(float4*)&p[8]  = *(const float4*)&Ps[qi][k0 + 8];
      *(float4*)&p[12] = *(const float4*)&Ps[qi][k0 + 12];
#pragma unroll
      for (int kk = 0; kk < 16; ++kk) {
        const float* vr = &Vs[k0 + kk][u * 16];
        const float4 v0 = *(const float4*)vr;
        const float4 v1 = *(const float4*)(vr + 4);
        const float4 v2 = *(const float4*)(vr + 8);
        const float4 v3 = *(const float4*)(vr + 12);
        O[0]  = fmaf(p[kk], v0.x, O[0]);  O[1]  = fmaf(p[kk], v0.y, O[1]);
        O[2]  = fmaf(p[kk], v0.z, O[2]);  O[3]  = fmaf(p[kk], v0.w, O[3]);
        O[4]  = fmaf(p[kk], v1.x, O[4]);  O[5]  = fmaf(p[kk], v1.y, O[5]);
        O[6]  = fmaf(p[kk], v1.z, O[6]);  O[7]  = fmaf(p[kk], v1.w, O[7]);
        O[8]  = fmaf(p[kk], v2.x, O[8]);  O[9]  = fmaf(p[kk], v2.y, O[9]);
        O[10] = fmaf(p[kk], v2.z, O[10]); O[11] = fmaf(p[kk], v2.w, O[11]);
        O[12] = fmaf(p[kk], v3.x, O[12]); O[13] = fmaf(p[kk], v3.y, O[13]);
        O[14] = fmaf(p[kk], v3.z, O[14]); O[15] = fmaf(p[kk], v3.w, O[15]);
      }
    }
  }

  const float invl = 1.f / l_run;
  __hip_bfloat16* dst = att + base + (size_t)(qt * 64 + qi) * 64 + u * 16;
  u16x8 o0, o1;
#pragma unroll
  for (int f = 0; f < 8; ++f) { o0[f] = f2bf(O[f] * invl); o1[f] = f2bf(O[8 + f] * invl); }
  *(u16x8*)dst = o0;
  *(u16x8*)(dst + 8) = o1;
}

// =====================================================================
// Launch
// =====================================================================
extern "C" void kernel_launch(void* const* d_in, const int* in_sizes, int n_in,
                              void* d_out, int out_size, void* d_ws, size_t ws_size,
                              hipStream_t stream) {
  const float* x      = (const float*)d_in[0];
  const float* loc_wq = (const float*)d_in[1];
  const float* loc_bq = (const float*)d_in[2];
  const float* loc_wk = (const float*)d_in[3];
  const float* loc_bk = (const float*)d_in[4];
  const float* loc_wv = (const float*)d_in[5];
  const float* loc_bv = (const float*)d_in[6];
  const float* loc_wo = (const float*)d_in[7];
  const float* loc_bo = (const float*)d_in[8];
  const float* g_wq  = (const float*)d_in[9];
  const float* g_bq  = (const float*)d_in[10];
  const float* g_wk  = (const float*)d_in[11];
  const float* g_bk  = (const float*)d_in[12];
  const float* g_wv  = (const float*)d_in[13];
  const float* g_bv  = (const float*)d_in[14];
  const float* g_wo  = (const float*)d_in[15];
  const float* g_bo  = (const float*)d_in[16];
  const float* out_w = (const float*)d_in[17];
  const float* out_b = (const float*)d_in[18];
  float* out = (float*)d_out;

  __hip_bfloat16* wsb = (__hip_bfloat16*)d_ws;
  const size_t SZ = (size_t)8192 * 512;   // activation matrix elems
  const size_t MS = (size_t)512 * 512;    // weight matrix elems
  __hip_bfloat16* xb    = wsb;                       // 4.19M
  __hip_bfloat16* WT    = wsb + SZ;                  // 20 matrices
  __hip_bfloat16* Xq    = wsb + SZ + 20 * MS;
  __hip_bfloat16* Xk    = Xq + SZ;
  __hip_bfloat16* Xv    = Xq + 2 * SZ;
  __hip_bfloat16* abar  = Xq + 3 * SZ;
  __hip_bfloat16* feats = Xq + 4 * SZ;

  const dim3 thr(256);

  // ---- one-time prep: cast x, transpose+cast all weights ----
  cast_x_kernel<<<2048, thr, 0, stream>>>(x, xb);
  // WT slots: 0-2 loc_q, 3-5 loc_k, 6-8 loc_v, 9-11 loc_o,
  //           12 g_q, 13 g_k, 14 g_v, 15 g_o, 16-19 out parts
  transpose_cast_kernel<<<dim3(256, 3), thr, 0, stream>>>(loc_wq, WT + 0 * MS);
  transpose_cast_kernel<<<dim3(256, 3), thr, 0, stream>>>(loc_wk, WT + 3 * MS);
  transpose_cast_kernel<<<dim3(256, 3), thr, 0, stream>>>(loc_wv, WT + 6 * MS);
  transpose_cast_kernel<<<dim3(256, 3), thr, 0, stream>>>(loc_wo, WT + 9 * MS);
  transpose_cast_kernel<<<dim3(256, 1), thr, 0, stream>>>(g_wq, WT + 12 * MS);
  transpose_cast_kernel<<<dim3(256, 1), thr, 0, stream>>>(g_wk, WT + 13 * MS);
  transpose_cast_kernel<<<dim3(256, 1), thr, 0, stream>>>(g_wv, WT + 14 * MS);
  transpose_cast_kernel<<<dim3(256, 1), thr, 0, stream>>>(g_wo, WT + 15 * MS);
  transpose_cast_kernel<<<dim3(256, 4), thr, 0, stream>>>(out_w, WT + 16 * MS);

  const dim3 ggrid(4, 128);        // N/128, M/64
  const dim3 gqkv(4, 128, 3);

  for (int lv = 0; lv < 3; ++lv) {
    gemm_qkv_kernel<<<gqkv, thr, 0, stream>>>(
        xb, WT + lv * MS, 3 * MS,
        loc_bq + lv * 512, loc_bk + lv * 512, loc_bv + lv * 512, Xq);

    if (lv == 0)
      local_attn_kernel<3><<<2048, thr, 0, stream>>>(
          Xq, Xk, Xv, loc_bq + lv * 512, loc_bk + lv * 512, loc_bv + lv * 512, abar);
    else if (lv == 1)
      local_attn_kernel<5><<<2048, thr, 0, stream>>>(
          Xq, Xk, Xv, loc_bq + lv * 512, loc_bk + lv * 512, loc_bv + lv * 512, abar);
    else
      local_attn_kernel<7><<<2048, thr, 0, stream>>>(
          Xq, Xk, Xv, loc_bq + lv * 512, loc_bk + lv * 512, loc_bv + lv * 512, abar);

    gemm_one_kernel<<<ggrid, thr, 0, stream>>>(abar, WT + (9 + lv) * MS,
                                               loc_bo + lv * 512, feats, nullptr, 0);
    gemm_one_kernel<<<ggrid, thr, 0, stream>>>(feats, WT + (16 + lv) * MS,
                                               lv == 0 ? out_b : nullptr, nullptr, out,
                                               lv == 0 ? 1 : 2);
  }

  // global branch
  gemm_qkv_kernel<<<gqkv, thr, 0, stream>>>(xb, WT + 12 * MS, MS, g_bq, g_bk, g_bv, Xq);
  global_attn_kernel<<<dim3(16, 64), thr, 0, stream>>>(Xq, Xk, Xv, abar);
  gemm_one_kernel<<<ggrid, thr, 0, stream>>>(abar, WT + 15 * MS, g_bo, feats, nullptr, 0);
  gemm_one_kernel<<<ggrid, thr, 0, stream>>>(feats, WT + 19 * MS, nullptr, nullptr, out, 2);
}

// Round 3
// 399.757 us; speedup vs baseline: 5.1758x; 1.8678x over previous
//
#include <hip/hip_runtime.h>
#include <hip/hip_bf16.h>
#include <cstddef>

#define T_SEQ 1024
#define D_MODEL 512

typedef __attribute__((ext_vector_type(8))) __bf16 bf16x8;
typedef __attribute__((ext_vector_type(4))) float f32x4;
typedef __attribute__((ext_vector_type(16))) float f32x16;
typedef __attribute__((ext_vector_type(8))) unsigned short u16x8;
typedef __attribute__((ext_vector_type(4))) unsigned int u32x4;

typedef const unsigned int __attribute__((address_space(1)))* gas1_t;
typedef unsigned int __attribute__((address_space(3)))* las3_t;

__device__ __forceinline__ void gload_lds16(const void* g, void* l) {
  __builtin_amdgcn_global_load_lds((gas1_t)g, (las3_t)l, 16, 0, 0);
}

__device__ __forceinline__ float bf2f(unsigned short u) {
  return __uint_as_float(((unsigned)u) << 16);
}
__device__ __forceinline__ unsigned short f2bf(float f) {
  __hip_bfloat16 h = __float2bfloat16(f);
  return *(unsigned short*)&h;
}

#define CVTPK(dst, a, b) \
  asm("v_cvt_pk_bf16_f32 %0, %1, %2" : "=v"(dst) : "v"(a), "v"(b))

// exchange lane halves between two dwords:
// after: a = {a.lo(lanes0-31), b.lo}, b = {a.hi, b.hi}
__device__ __forceinline__ void swap32(unsigned& a, unsigned& b, int lane) {
  const unsigned ax = __shfl_xor(a, 32);
  const unsigned bx = __shfl_xor(b, 32);
  const bool lo = lane < 32;
  const unsigned na = lo ? a : bx;
  const unsigned nb = lo ? ax : b;
  a = na; b = nb;
}

// =====================================================================
// Cast x fp32 -> bf16 (each thread 8 elems)
// =====================================================================
__global__ __launch_bounds__(256)
void cast_x_kernel(const float* __restrict__ in, __hip_bfloat16* __restrict__ out) {
  const int i = (blockIdx.x * 256 + threadIdx.x) * 8;
  const float4 a = *(const float4*)(in + i);
  const float4 b = *(const float4*)(in + i + 4);
  u16x8 o;
  o[0] = f2bf(a.x); o[1] = f2bf(a.y); o[2] = f2bf(a.z); o[3] = f2bf(a.w);
  o[4] = f2bf(b.x); o[5] = f2bf(b.y); o[6] = f2bf(b.z); o[7] = f2bf(b.w);
  *(u16x8*)(out + i) = o;
}

// =====================================================================
// Transpose+cast 512x512 fp32 matrices to bf16: dst[n][k] = src[k][n].
// =====================================================================
__global__ __launch_bounds__(256)
void transpose_cast_kernel(const float* __restrict__ src, __hip_bfloat16* __restrict__ dst) {
  __shared__ float tile[32][33];
  const float* W = src + (size_t)blockIdx.y * 262144;
  __hip_bfloat16* WT = dst + (size_t)blockIdx.y * 262144;
  const int tk = (blockIdx.x & 15) * 32;
  const int tn = (blockIdx.x >> 4) * 32;
  const int t = threadIdx.x;
  const int r = t >> 3, c4 = (t & 7) * 4;
  const float4 v = *(const float4*)(W + (size_t)(tk + r) * 512 + tn + c4);
  tile[r][c4 + 0] = v.x; tile[r][c4 + 1] = v.y;
  tile[r][c4 + 2] = v.z; tile[r][c4 + 3] = v.w;
  __syncthreads();
  ushort4 o;
  o.x = f2bf(tile[c4 + 0][r]); o.y = f2bf(tile[c4 + 1][r]);
  o.z = f2bf(tile[c4 + 2][r]); o.w = f2bf(tile[c4 + 3][r]);
  *(ushort4*)(WT + (size_t)(tn + r) * 512 + tk + c4) = o;
}

// =====================================================================
// MFMA GEMM core (unchanged from round 2): BM=64 BN=128 BK=32.
// =====================================================================
__device__ __forceinline__ void gemm_core_512(
    const __hip_bfloat16* __restrict__ A, const __hip_bfloat16* __restrict__ BT,
    __hip_bfloat16* As, __hip_bfloat16* Bs, int row0, int col0, f32x4 acc[2][4]) {
  const int tid = threadIdx.x;
  const int wv = tid >> 6, lane = tid & 63;
  const int g = lane >> 4, r16 = lane & 15;
  const int wm = wv >> 1, wn = wv & 1;
#pragma unroll
  for (int m = 0; m < 2; ++m)
#pragma unroll
    for (int n = 0; n < 4; ++n) acc[m][n] = (f32x4)(0.0f);
  const char* Ab = (const char*)A;
  const char* Bb = (const char*)BT;
  for (int k0 = 0; k0 < 512; k0 += 32) {
    {
      const int row = tid >> 2, off = (tid & 3) << 4;
      gload_lds16(Ab + (size_t)(row0 + row) * 1024 + k0 * 2 + off,
                  (char*)As + (wv << 10));
    }
    {
      const int row = tid >> 2, off = (tid & 3) << 4;
      gload_lds16(Bb + (size_t)(col0 + row) * 1024 + k0 * 2 + off,
                  (char*)Bs + (wv << 10));
      const int c2 = tid + 256;
      const int row2 = c2 >> 2, off2 = (c2 & 3) << 4;
      gload_lds16(Bb + (size_t)(col0 + row2) * 1024 + k0 * 2 + off2,
                  (char*)Bs + 4096 + (wv << 10));
    }
    __syncthreads();
    bf16x8 a[2], b[4];
#pragma unroll
    for (int m = 0; m < 2; ++m)
      a[m] = *(const bf16x8*)(As + (wm * 32 + m * 16 + r16) * 32 + g * 8);
#pragma unroll
    for (int n = 0; n < 4; ++n)
      b[n] = *(const bf16x8*)(Bs + (wn * 64 + n * 16 + r16) * 32 + g * 8);
#pragma unroll
    for (int m = 0; m < 2; ++m)
#pragma unroll
      for (int n = 0; n < 4; ++n)
        acc[m][n] = __builtin_amdgcn_mfma_f32_16x16x32_bf16(a[m], b[n], acc[m][n], 0, 0, 0);
    __syncthreads();
  }
}

__global__ __launch_bounds__(256, 2)
void gemm_qkv_kernel(const __hip_bfloat16* __restrict__ A,
                     const __hip_bfloat16* __restrict__ WT_base, size_t wt_stride,
                     const float* __restrict__ b0, const float* __restrict__ b1,
                     const float* __restrict__ b2,
                     __hip_bfloat16* __restrict__ out_base) {
  __shared__ __attribute__((aligned(16))) __hip_bfloat16 As[2048];
  __shared__ __attribute__((aligned(16))) __hip_bfloat16 Bs[4096];
  const int z = blockIdx.z;
  const __hip_bfloat16* WT = WT_base + (size_t)z * wt_stride;
  const float* bias = (z == 0) ? b0 : (z == 1) ? b1 : b2;
  __hip_bfloat16* C = out_base + (size_t)z * (size_t)(8192 * 512);
  const int row0 = blockIdx.y * 64, col0 = blockIdx.x * 128;
  f32x4 acc[2][4];
  gemm_core_512(A, WT, As, Bs, row0, col0, acc);
  const int lane = threadIdx.x & 63, wv = threadIdx.x >> 6;
  const int g = lane >> 4, r16 = lane & 15, wm = wv >> 1, wn = wv & 1;
#pragma unroll
  for (int n = 0; n < 4; ++n) {
    const int col = col0 + wn * 64 + n * 16 + r16;
    const float bn = bias[col];
#pragma unroll
    for (int m = 0; m < 2; ++m) {
      const int rowb = row0 + wm * 32 + m * 16 + g * 4;
#pragma unroll
      for (int r = 0; r < 4; ++r)
        C[(size_t)(rowb + r) * 512 + col] = __float2bfloat16(acc[m][n][r] + bn);
    }
  }
}

__global__ __launch_bounds__(256, 2)
void gemm_one_kernel(const __hip_bfloat16* __restrict__ A,
                     const __hip_bfloat16* __restrict__ WT,
                     const float* __restrict__ bias,
                     __hip_bfloat16* __restrict__ Cb, float* __restrict__ Cf,
                     int mode) {
  __shared__ __attribute__((aligned(16))) __hip_bfloat16 As[2048];
  __shared__ __attribute__((aligned(16))) __hip_bfloat16 Bs[4096];
  const int row0 = blockIdx.y * 64, col0 = blockIdx.x * 128;
  f32x4 acc[2][4];
  gemm_core_512(A, WT, As, Bs, row0, col0, acc);
  const int lane = threadIdx.x & 63, wv = threadIdx.x >> 6;
  const int g = lane >> 4, r16 = lane & 15, wm = wv >> 1, wn = wv & 1;
#pragma unroll
  for (int n = 0; n < 4; ++n) {
    const int col = col0 + wn * 64 + n * 16 + r16;
    const float bn = bias ? bias[col] : 0.f;
#pragma unroll
    for (int m = 0; m < 2; ++m) {
      const int rowb = row0 + wm * 32 + m * 16 + g * 4;
#pragma unroll
      for (int r = 0; r < 4; ++r) {
        const size_t idx = (size_t)(rowb + r) * 512 + col;
        if (mode == 0) Cb[idx] = __float2bfloat16(acc[m][n][r] + bn);
        else if (mode == 1) Cf[idx] = acc[m][n][r] + bn;
        else Cf[idx] += acc[m][n][r];
      }
    }
  }
}

// =====================================================================
// Local windowed attention (unchanged from round 2).
// =====================================================================
template <int W>
__global__ __launch_bounds__(256)
void local_attn_kernel(const __hip_bfloat16* __restrict__ Xq,
                       const __hip_bfloat16* __restrict__ Xk,
                       const __hip_bfloat16* __restrict__ Xv,
                       const float* __restrict__ bq, const float* __restrict__ bk,
                       const float* __restrict__ bv,
                       __hip_bfloat16* __restrict__ abar) {
  constexpr int PAD = (W - 1) / 2;
  __shared__ float att_lds[4][8 * W][68];
  const int wave = threadIdx.x >> 6;
  const int lane = threadIdx.x & 63;
  const int bt = (blockIdx.x << 2) + wave;
  const int b = bt >> 10, t = bt & 1023;
  const int h = lane >> 3;
  const int colb = (lane & 7) * 8;

  float q[W][8];
#pragma unroll
  for (int p = 0; p < W; ++p) {
    const int m = h * W + p, j = m >> 3, c = m & 7;
    const int s = t + j - PAD;
    if (s >= 0 && s < T_SEQ) {
      const u16x8 v = *(const u16x8*)(Xq + ((size_t)(b * T_SEQ + s) << 9) + c * 64 + colb);
#pragma unroll
      for (int e = 0; e < 8; ++e) q[p][e] = bf2f(v[e]);
    } else {
      const float* src = bq + c * 64 + colb;
      const float4 v0 = *(const float4*)src, v1 = *(const float4*)(src + 4);
      q[p][0] = v0.x; q[p][1] = v0.y; q[p][2] = v0.z; q[p][3] = v0.w;
      q[p][4] = v1.x; q[p][5] = v1.y; q[p][6] = v1.z; q[p][7] = v1.w;
    }
  }

  float sc[W][W];
#pragma unroll
  for (int pk = 0; pk < W; ++pk) {
    const int m = h * W + pk, j = m >> 3, c = m & 7;
    const int s = t + j - PAD;
    float kr[8];
    if (s >= 0 && s < T_SEQ) {
      const u16x8 v = *(const u16x8*)(Xk + ((size_t)(b * T_SEQ + s) << 9) + c * 64 + colb);
#pragma unroll
      for (int e = 0; e < 8; ++e) kr[e] = bf2f(v[e]);
    } else {
      const float* src = bk + c * 64 + colb;
      const float4 v0 = *(const float4*)src, v1 = *(const float4*)(src + 4);
      kr[0] = v0.x; kr[1] = v0.y; kr[2] = v0.z; kr[3] = v0.w;
      kr[4] = v1.x; kr[5] = v1.y; kr[6] = v1.z; kr[7] = v1.w;
    }
#pragma unroll
    for (int pq = 0; pq < W; ++pq) {
      float d = 0.f;
#pragma unroll
      for (int e = 0; e < 8; ++e) d = fmaf(q[pq][e], kr[e], d);
      d += __shfl_xor(d, 1);
      d += __shfl_xor(d, 2);
      d += __shfl_xor(d, 4);
      sc[pq][pk] = d * 0.125f;
    }
  }

#pragma unroll
  for (int pq = 0; pq < W; ++pq) {
    float mx = sc[pq][0];
#pragma unroll
    for (int pk = 1; pk < W; ++pk) mx = fmaxf(mx, sc[pq][pk]);
    float sum = 0.f;
#pragma unroll
    for (int pk = 0; pk < W; ++pk) {
      const float e = __expf(sc[pq][pk] - mx);
      sc[pq][pk] = e;
      sum += e;
    }
    const float inv = 1.f / sum;
#pragma unroll
    for (int pk = 0; pk < W; ++pk) sc[pq][pk] *= inv;
  }

  float av[W][8];
#pragma unroll
  for (int p = 0; p < W; ++p)
#pragma unroll
    for (int e = 0; e < 8; ++e) av[p][e] = 0.f;
#pragma unroll
  for (int pk = 0; pk < W; ++pk) {
    const int m = h * W + pk, j = m >> 3, c = m & 7;
    const int s = t + j - PAD;
    float vr[8];
    if (s >= 0 && s < T_SEQ) {
      const u16x8 v = *(const u16x8*)(Xv + ((size_t)(b * T_SEQ + s) << 9) + c * 64 + colb);
#pragma unroll
      for (int e = 0; e < 8; ++e) vr[e] = bf2f(v[e]);
    } else {
      const float* src = bv + c * 64 + colb;
      const float4 v0 = *(const float4*)src, v1 = *(const float4*)(src + 4);
      vr[0] = v0.x; vr[1] = v0.y; vr[2] = v0.z; vr[3] = v0.w;
      vr[4] = v1.x; vr[5] = v1.y; vr[6] = v1.z; vr[7] = v1.w;
    }
#pragma unroll
    for (int pq = 0; pq < W; ++pq)
#pragma unroll
      for (int e = 0; e < 8; ++e) av[pq][e] = fmaf(sc[pq][pk], vr[e], av[pq][e]);
  }

#pragma unroll
  for (int p = 0; p < W; ++p) {
    const int m = h * W + p;
    *(float4*)&att_lds[wave][m][colb] =
        make_float4(av[p][0], av[p][1], av[p][2], av[p][3]);
    *(float4*)&att_lds[wave][m][colb + 4] =
        make_float4(av[p][4], av[p][5], av[p][6], av[p][7]);
  }
  __syncthreads();
  const int cc = lane >> 3, fb = (lane & 7) * 8;
  float o[8] = {0.f, 0.f, 0.f, 0.f, 0.f, 0.f, 0.f, 0.f};
#pragma unroll
  for (int j = 0; j < W; ++j) {
    const float* sp = &att_lds[wave][j * 8 + cc][fb];
    const float4 a0 = *(const float4*)sp, a1 = *(const float4*)(sp + 4);
    o[0] += a0.x; o[1] += a0.y; o[2] += a0.z; o[3] += a0.w;
    o[4] += a1.x; o[5] += a1.y; o[6] += a1.z; o[7] += a1.w;
  }
  const float invw = 1.f / (float)W;
  u16x8 ov;
#pragma unroll
  for (int e = 0; e < 8; ++e) ov[e] = f2bf(o[e] * invw);
  *(u16x8*)(abar + ((size_t)bt << 9) + lane * 8) = ov;
}

// =====================================================================
// Global attention, MFMA flash (32x32x16 bf16, swapped operands).
// Layout: Q/K/V at [bh][s][64] (pure reshape). Block = (qblk, bh),
// 4 waves x 32 q-rows = 128 q-rows/block. KVBLK=64, 16 iterations.
//  - S^T = mfma(K_frag, Q_frag): C/D col = q = lane&31 -> softmax stats
//    are lane-uniform; k-reduce = in-reg tree + shfl_xor(32).
//  - P redistribution: 8 cvt_pk_bf16 + 4 half-swaps per 32x32 block.
//  - O^T = mfma(V^T_frag, P^T_frag): alpha rescale needs no shuffles.
//  - V^T built in LDS (pair-packed dwords, XOR-swizzled rows), dbuf'd.
//  - K/Q frags load global->VGPR directly (L2-hot).
// =====================================================================
__global__ __launch_bounds__(256)
void global_attn_mfma_kernel(const __hip_bfloat16* __restrict__ Xq,
                             const __hip_bfloat16* __restrict__ Xk,
                             const __hip_bfloat16* __restrict__ Xv,
                             __hip_bfloat16* __restrict__ att) {
  __shared__ unsigned vt[2][2048];   // V^T: [buf][64 d-rows x 32 k-pair dwords]
  const int tid = threadIdx.x;
  const int lane = tid & 63;
  const int wv = tid >> 6;
  const int qblk = blockIdx.x;       // 0..7
  const int bh = blockIdx.y;         // 0..63
  const size_t base = (size_t)bh << 16;
  const int c = lane & 31;
  const int g = lane >> 5;
  const int q0 = qblk * 128 + wv * 32;

  const __hip_bfloat16* Qp = Xq + base;
  const __hip_bfloat16* Kp = Xk + base;
  const __hip_bfloat16* Vp = Xv + base;

  // Q B-frags: lane holds Q[q0+c][16s + 8g + j]
  bf16x8 qf[4];
#pragma unroll
  for (int s = 0; s < 4; ++s)
    qf[s] = *(const bf16x8*)(Qp + (size_t)(q0 + c) * 64 + s * 16 + g * 8);

  // V staging mapping: k2 = k-pair (0..31), dblk = 8-d block (0..7)
  const int k2 = tid & 31, dblk = tid >> 5;

  bf16x8 kf[2][4];
  u16x8 v0, v1, v0n, v1n;

  // prologue: tile 0
  v0 = *(const u16x8*)(Vp + (size_t)(2 * k2) * 64 + dblk * 8);
  v1 = *(const u16x8*)(Vp + (size_t)(2 * k2 + 1) * 64 + dblk * 8);
#pragma unroll
  for (int kb = 0; kb < 2; ++kb)
#pragma unroll
    for (int s = 0; s < 4; ++s)
      kf[kb][s] = *(const bf16x8*)(Kp + (size_t)(kb * 32 + c) * 64 + s * 16 + g * 8);

  f32x16 Oa = (f32x16)(0.0f), Ob = (f32x16)(0.0f);
  float m_run = -3e38f, l_run = 0.f;

  for (int kt = 0; kt < 16; ++kt) {
    // ---- stage V^T tile kt into LDS buf[kt&1] ----
    unsigned* vb = &vt[kt & 1][0];
#pragma unroll
    for (int jj = 0; jj < 8; ++jj) {
      const int d = dblk * 8 + jj;
      const unsigned dw = (unsigned)v0[jj] | ((unsigned)v1[jj] << 16);
      const int byte = (d * 128 + k2 * 4) ^ ((d & 7) << 4);
      vb[byte >> 2] = dw;
    }
    // prefetch next V tile into regs
    if (kt < 15) {
      const __hip_bfloat16* vsrc = Vp + (size_t)((kt + 1) * 64 + 2 * k2) * 64 + dblk * 8;
      v0n = *(const u16x8*)vsrc;
      v1n = *(const u16x8*)(vsrc + 64);
    }
    __syncthreads();

    // ---- QK^T: S^T blocks (k rows x q cols) ----
    f32x16 sa = (f32x16)(0.0f), sb = (f32x16)(0.0f);
#pragma unroll
    for (int s = 0; s < 4; ++s)
      sa = __builtin_amdgcn_mfma_f32_32x32x16_bf16(kf[0][s], qf[s], sa, 0, 0, 0);
#pragma unroll
    for (int s = 0; s < 4; ++s)
      sb = __builtin_amdgcn_mfma_f32_32x32x16_bf16(kf[1][s], qf[s], sb, 0, 0, 0);

    // prefetch K frags for next tile (dead regs after the mfmas above)
    if (kt < 15) {
#pragma unroll
      for (int kb = 0; kb < 2; ++kb)
#pragma unroll
        for (int s = 0; s < 4; ++s)
          kf[kb][s] = *(const bf16x8*)(Kp + (size_t)((kt + 1) * 64 + kb * 32 + c) * 64 +
                                       s * 16 + g * 8);
    }

    // ---- online softmax over k (rows); q = lane&31, lane-uniform stats ----
    float mx = sa[0];
#pragma unroll
    for (int r = 1; r < 16; ++r) mx = fmaxf(mx, sa[r]);
#pragma unroll
    for (int r = 0; r < 16; ++r) mx = fmaxf(mx, sb[r]);
    mx = fmaxf(mx, __shfl_xor(mx, 32));
    const float m_new = fmaxf(m_run, mx * 0.125f);
    const float alpha = __expf(m_run - m_new);

    float p0[16], p1[16];
    float lsum = 0.f;
#pragma unroll
    for (int r = 0; r < 16; ++r) { p0[r] = __expf(fmaf(sa[r], 0.125f, -m_new)); lsum += p0[r]; }
#pragma unroll
    for (int r = 0; r < 16; ++r) { p1[r] = __expf(fmaf(sb[r], 0.125f, -m_new)); lsum += p1[r]; }
    lsum += __shfl_xor(lsum, 32);
    l_run = fmaf(l_run, alpha, lsum);
    m_run = m_new;
#pragma unroll
    for (int r = 0; r < 16; ++r) { Oa[r] *= alpha; Ob[r] *= alpha; }

    // ---- redistribute P: C/D reg layout -> B-operand frags ----
    unsigned bw[2][2][4];
#define REDIST(pb, kb_)                                                  \
    {                                                                    \
      unsigned t0, t1, t2, t3, t4, t5, t6, t7;                           \
      CVTPK(t0, pb[0], pb[1]);   CVTPK(t1, pb[2], pb[3]);                \
      CVTPK(t2, pb[4], pb[5]);   CVTPK(t3, pb[6], pb[7]);                \
      CVTPK(t4, pb[8], pb[9]);   CVTPK(t5, pb[10], pb[11]);              \
      CVTPK(t6, pb[12], pb[13]); CVTPK(t7, pb[14], pb[15]);              \
      swap32(t0, t2, lane); swap32(t1, t3, lane);                        \
      swap32(t4, t6, lane); swap32(t5, t7, lane);                        \
      bw[kb_][0][0] = t0; bw[kb_][0][1] = t1; bw[kb_][0][2] = t2;        \
      bw[kb_][0][3] = t3;                                                \
      bw[kb_][1][0] = t4; bw[kb_][1][1] = t5; bw[kb_][1][2] = t6;        \
      bw[kb_][1][3] = t7;                                                \
    }
    REDIST(p0, 0)
    REDIST(p1, 1)
#undef REDIST

    // ---- PV: O^T += V^T_frag @ P^T_frag ----
    const unsigned* vbr = &vt[kt & 1][0];
#pragma unroll
    for (int kb = 0; kb < 2; ++kb)
#pragma unroll
      for (int st = 0; st < 2; ++st) {
        const u32x4 pw = { bw[kb][st][0], bw[kb][st][1], bw[kb][st][2], bw[kb][st][3] };
        const bf16x8 pf = __builtin_bit_cast(bf16x8, pw);
        {
          const int row = c;
          const int off = (row * 128 + (kb * 64 + st * 32 + g * 16)) ^ ((row & 7) << 4);
          const bf16x8 va = __builtin_bit_cast(bf16x8, *(const u32x4*)((const char*)vbr + off));
          Oa = __builtin_amdgcn_mfma_f32_32x32x16_bf16(va, pf, Oa, 0, 0, 0);
        }
        {
          const int row = 32 + c;
          const int off = (row * 128 + (kb * 64 + st * 32 + g * 16)) ^ ((row & 7) << 4);
          const bf16x8 va = __builtin_bit_cast(bf16x8, *(const u32x4*)((const char*)vbr + off));
          Ob = __builtin_amdgcn_mfma_f32_32x32x16_bf16(va, pf, Ob, 0, 0, 0);
        }
      }

    v0 = v0n; v1 = v1n;
  }

  // ---- epilogue: O^T rows d = (r&3)+8(r>>2)+4g (+32 for Ob), col q=c ----
  const float inv = 1.f / l_run;
  __hip_bfloat16* drow = att + base + (size_t)(q0 + c) * 64;
#pragma unroll
  for (int qd = 0; qd < 4; ++qd) {
    unsigned lo, hi;
    {
      const float a0 = Oa[4 * qd + 0] * inv, a1 = Oa[4 * qd + 1] * inv;
      const float a2 = Oa[4 * qd + 2] * inv, a3 = Oa[4 * qd + 3] * inv;
      CVTPK(lo, a0, a1); CVTPK(hi, a2, a3);
      uint2 w; w.x = lo; w.y = hi;
      *(uint2*)(drow + 8 * qd + 4 * g) = w;
    }
    {
      const float a0 = Ob[4 * qd + 0] * inv, a1 = Ob[4 * qd + 1] * inv;
      const float a2 = Ob[4 * qd + 2] * inv, a3 = Ob[4 * qd + 3] * inv;
      CVTPK(lo, a0, a1); CVTPK(hi, a2, a3);
      uint2 w; w.x = lo; w.y = hi;
      *(uint2*)(drow + 32 + 8 * qd + 4 * g) = w;
    }
  }
}

// =====================================================================
// Launch
// =====================================================================
extern "C" void kernel_launch(void* const* d_in, const int* in_sizes, int n_in,
                              void* d_out, int out_size, void* d_ws, size_t ws_size,
                              hipStream_t stream) {
  const float* x      = (const float*)d_in[0];
  const float* loc_wq = (const float*)d_in[1];
  const float* loc_bq = (const float*)d_in[2];
  const float* loc_wk = (const float*)d_in[3];
  const float* loc_bk = (const float*)d_in[4];
  const float* loc_wv = (const float*)d_in[5];
  const float* loc_bv = (const float*)d_in[6];
  const float* loc_wo = (const float*)d_in[7];
  const float* loc_bo = (const float*)d_in[8];
  const float* g_wq  = (const float*)d_in[9];
  const float* g_bq  = (const float*)d_in[10];
  const float* g_wk  = (const float*)d_in[11];
  const float* g_bk  = (const float*)d_in[12];
  const float* g_wv  = (const float*)d_in[13];
  const float* g_bv  = (const float*)d_in[14];
  const float* g_wo  = (const float*)d_in[15];
  const float* g_bo  = (const float*)d_in[16];
  const float* out_w = (const float*)d_in[17];
  const float* out_b = (const float*)d_in[18];
  float* out = (float*)d_out;

  __hip_bfloat16* wsb = (__hip_bfloat16*)d_ws;
  const size_t SZ = (size_t)8192 * 512;
  const size_t MS = (size_t)512 * 512;
  __hip_bfloat16* xb    = wsb;
  __hip_bfloat16* WT    = wsb + SZ;
  __hip_bfloat16* Xq    = wsb + SZ + 20 * MS;
  __hip_bfloat16* Xk    = Xq + SZ;
  __hip_bfloat16* Xv    = Xq + 2 * SZ;
  __hip_bfloat16* abar  = Xq + 3 * SZ;
  __hip_bfloat16* feats = Xq + 4 * SZ;

  const dim3 thr(256);

  cast_x_kernel<<<2048, thr, 0, stream>>>(x, xb);
  transpose_cast_kernel<<<dim3(256, 3), thr, 0, stream>>>(loc_wq, WT + 0 * MS);
  transpose_cast_kernel<<<dim3(256, 3), thr, 0, stream>>>(loc_wk, WT + 3 * MS);
  transpose_cast_kernel<<<dim3(256, 3), thr, 0, stream>>>(loc_wv, WT + 6 * MS);
  transpose_cast_kernel<<<dim3(256, 3), thr, 0, stream>>>(loc_wo, WT + 9 * MS);
  transpose_cast_kernel<<<dim3(256, 1), thr, 0, stream>>>(g_wq, WT + 12 * MS);
  transpose_cast_kernel<<<dim3(256, 1), thr, 0, stream>>>(g_wk, WT + 13 * MS);
  transpose_cast_kernel<<<dim3(256, 1), thr, 0, stream>>>(g_wv, WT + 14 * MS);
  transpose_cast_kernel<<<dim3(256, 1), thr, 0, stream>>>(g_wo, WT + 15 * MS);
  transpose_cast_kernel<<<dim3(256, 4), thr, 0, stream>>>(out_w, WT + 16 * MS);

  const dim3 ggrid(4, 128);
  const dim3 gqkv(4, 128, 3);

  for (int lv = 0; lv < 3; ++lv) {
    gemm_qkv_kernel<<<gqkv, thr, 0, stream>>>(
        xb, WT + lv * MS, 3 * MS,
        loc_bq + lv * 512, loc_bk + lv * 512, loc_bv + lv * 512, Xq);

    if (lv == 0)
      local_attn_kernel<3><<<2048, thr, 0, stream>>>(
          Xq, Xk, Xv, loc_bq + lv * 512, loc_bk + lv * 512, loc_bv + lv * 512, abar);
    else if (lv == 1)
      local_attn_kernel<5><<<2048, thr, 0, stream>>>(
          Xq, Xk, Xv, loc_bq + lv * 512, loc_bk + lv * 512, loc_bv + lv * 512, abar);
    else
      local_attn_kernel<7><<<2048, thr, 0, stream>>>(
          Xq, Xk, Xv, loc_bq + lv * 512, loc_bk + lv * 512, loc_bv + lv * 512, abar);

    gemm_one_kernel<<<ggrid, thr, 0, stream>>>(abar, WT + (9 + lv) * MS,
                                               loc_bo + lv * 512, feats, nullptr, 0);
    gemm_one_kernel<<<ggrid, thr, 0, stream>>>(feats, WT + (16 + lv) * MS,
                                               lv == 0 ? out_b : nullptr, nullptr, out,
                                               lv == 0 ? 1 : 2);
  }

  gemm_qkv_kernel<<<gqkv, thr, 0, stream>>>(xb, WT + 12 * MS, MS, g_bq, g_bk, g_bv, Xq);
  global_attn_mfma_kernel<<<dim3(8, 64), thr, 0, stream>>>(Xq, Xk, Xv, abar);
  gemm_one_kernel<<<ggrid, thr, 0, stream>>>(abar, WT + 15 * MS, g_bo, feats, nullptr, 0);
  gemm_one_kernel<<<ggrid, thr, 0, stream>>>(feats, WT + 19 * MS, nullptr, nullptr, out, 2);
}

// Round 4
// 361.836 us; speedup vs baseline: 5.7182x; 1.1048x over previous
//
#include <hip/hip_runtime.h>
#include <hip/hip_bf16.h>
#include <cstddef>

#define T_SEQ 1024
#define D_MODEL 512

typedef __attribute__((ext_vector_type(8))) __bf16 bf16x8;
typedef __attribute__((ext_vector_type(4))) float f32x4;
typedef __attribute__((ext_vector_type(16))) float f32x16;
typedef __attribute__((ext_vector_type(8))) unsigned short u16x8;
typedef __attribute__((ext_vector_type(4))) unsigned int u32x4;

typedef const unsigned int __attribute__((address_space(1)))* gas1_t;
typedef unsigned int __attribute__((address_space(3)))* las3_t;

__device__ __forceinline__ void gload_lds16(const void* g, void* l) {
  __builtin_amdgcn_global_load_lds((gas1_t)g, (las3_t)l, 16, 0, 0);
}

__device__ __forceinline__ float bf2f(unsigned short u) {
  return __uint_as_float(((unsigned)u) << 16);
}
__device__ __forceinline__ unsigned short f2bf(float f) {
  __hip_bfloat16 h = __float2bfloat16(f);
  return *(unsigned short*)&h;
}

#define CVTPK(dst, a, b) \
  asm("v_cvt_pk_bf16_f32 %0, %1, %2" : "=v"(dst) : "v"(a), "v"(b))

// exchange lane halves between two dwords:
// after: a = {a.lo(lanes0-31), b.lo}, b = {a.hi, b.hi}
__device__ __forceinline__ void swap32(unsigned& a, unsigned& b, int lane) {
  const unsigned ax = __shfl_xor(a, 32);
  const unsigned bx = __shfl_xor(b, 32);
  const bool lo = lane < 32;
  const unsigned na = lo ? a : bx;
  const unsigned nb = lo ? ax : b;
  a = na; b = nb;
}

// =====================================================================
// Cast fp32 -> bf16 (each thread 8 elems); used for x and for wo (plain).
// =====================================================================
__global__ __launch_bounds__(256)
void cast_x_kernel(const float* __restrict__ in, __hip_bfloat16* __restrict__ out) {
  const int i = (blockIdx.x * 256 + threadIdx.x) * 8;
  const float4 a = *(const float4*)(in + i);
  const float4 b = *(const float4*)(in + i + 4);
  u16x8 o;
  o[0] = f2bf(a.x); o[1] = f2bf(a.y); o[2] = f2bf(a.z); o[3] = f2bf(a.w);
  o[4] = f2bf(b.x); o[5] = f2bf(b.y); o[6] = f2bf(b.z); o[7] = f2bf(b.w);
  *(u16x8*)(out + i) = o;
}

// =====================================================================
// Transpose+cast 512x512 fp32 matrices to bf16: dst[n][k] = src[k][n].
// =====================================================================
__global__ __launch_bounds__(256)
void transpose_cast_kernel(const float* __restrict__ src, __hip_bfloat16* __restrict__ dst) {
  __shared__ float tile[32][33];
  const float* W = src + (size_t)blockIdx.y * 262144;
  __hip_bfloat16* WT = dst + (size_t)blockIdx.y * 262144;
  const int tk = (blockIdx.x & 15) * 32;
  const int tn = (blockIdx.x >> 4) * 32;
  const int t = threadIdx.x;
  const int r = t >> 3, c4 = (t & 7) * 4;
  const float4 v = *(const float4*)(W + (size_t)(tk + r) * 512 + tn + c4);
  tile[r][c4 + 0] = v.x; tile[r][c4 + 1] = v.y;
  tile[r][c4 + 2] = v.z; tile[r][c4 + 3] = v.w;
  __syncthreads();
  ushort4 o;
  o.x = f2bf(tile[c4 + 0][r]); o.y = f2bf(tile[c4 + 1][r]);
  o.z = f2bf(tile[c4 + 2][r]); o.w = f2bf(tile[c4 + 3][r]);
  *(ushort4*)(WT + (size_t)(tn + r) * 512 + tk + c4) = o;
}

// =====================================================================
// Fused bias: bfused[z][n] = bo_z @ out_w[z*512..] (+ out_b for z==0).
// =====================================================================
__global__ __launch_bounds__(256)
void bias_fuse_kernel(const float* __restrict__ loc_bo, const float* __restrict__ g_bo,
                      const float* __restrict__ out_w, const float* __restrict__ out_b,
                      float* __restrict__ bfused) {
  const int z = blockIdx.y;
  const int n = blockIdx.x * 256 + threadIdx.x;
  const float* bo = (z < 3) ? loc_bo + z * 512 : g_bo;
  const float* W = out_w + (size_t)z * 512 * 512;
  float acc = (z == 0) ? out_b[n] : 0.f;
  for (int m = 0; m < 512; ++m)
    acc = fmaf(bo[m], W[(size_t)m * 512 + n], acc);
  bfused[z * 512 + n] = acc;
}

// =====================================================================
// MFMA GEMM core: BM=64 BN=128 BK=32, A [Mx512] row-major bf16,
// BT [512x512] (B transposed) bf16.
// =====================================================================
__device__ __forceinline__ void gemm_core_512(
    const __hip_bfloat16* __restrict__ A, const __hip_bfloat16* __restrict__ BT,
    __hip_bfloat16* As, __hip_bfloat16* Bs, int row0, int col0, f32x4 acc[2][4]) {
  const int tid = threadIdx.x;
  const int wv = tid >> 6, lane = tid & 63;
  const int g = lane >> 4, r16 = lane & 15;
  const int wm = wv >> 1, wn = wv & 1;
#pragma unroll
  for (int m = 0; m < 2; ++m)
#pragma unroll
    for (int n = 0; n < 4; ++n) acc[m][n] = (f32x4)(0.0f);
  const char* Ab = (const char*)A;
  const char* Bb = (const char*)BT;
  for (int k0 = 0; k0 < 512; k0 += 32) {
    {
      const int row = tid >> 2, off = (tid & 3) << 4;
      gload_lds16(Ab + (size_t)(row0 + row) * 1024 + k0 * 2 + off,
                  (char*)As + (wv << 10));
    }
    {
      const int row = tid >> 2, off = (tid & 3) << 4;
      gload_lds16(Bb + (size_t)(col0 + row) * 1024 + k0 * 2 + off,
                  (char*)Bs + (wv << 10));
      const int c2 = tid + 256;
      const int row2 = c2 >> 2, off2 = (c2 & 3) << 4;
      gload_lds16(Bb + (size_t)(col0 + row2) * 1024 + k0 * 2 + off2,
                  (char*)Bs + 4096 + (wv << 10));
    }
    __syncthreads();
    bf16x8 a[2], b[4];
#pragma unroll
    for (int m = 0; m < 2; ++m)
      a[m] = *(const bf16x8*)(As + (wm * 32 + m * 16 + r16) * 32 + g * 8);
#pragma unroll
    for (int n = 0; n < 4; ++n)
      b[n] = *(const bf16x8*)(Bs + (wn * 64 + n * 16 + r16) * 32 + g * 8);
#pragma unroll
    for (int m = 0; m < 2; ++m)
#pragma unroll
      for (int n = 0; n < 4; ++n)
        acc[m][n] = __builtin_amdgcn_mfma_f32_16x16x32_bf16(a[m], b[n], acc[m][n], 0, 0, 0);
    __syncthreads();
  }
}

// Fused Q/K/V projection: blockIdx.z selects weight slot / bias / output.
__global__ __launch_bounds__(256, 2)
void gemm_qkv_kernel(const __hip_bfloat16* __restrict__ A,
                     const __hip_bfloat16* __restrict__ WT_base, size_t wt_stride,
                     const float* __restrict__ b0, const float* __restrict__ b1,
                     const float* __restrict__ b2,
                     __hip_bfloat16* __restrict__ out_base) {
  __shared__ __attribute__((aligned(16))) __hip_bfloat16 As[2048];
  __shared__ __attribute__((aligned(16))) __hip_bfloat16 Bs[4096];
  const int z = blockIdx.z;
  const __hip_bfloat16* WT = WT_base + (size_t)z * wt_stride;
  const float* bias = (z == 0) ? b0 : (z == 1) ? b1 : b2;
  __hip_bfloat16* C = out_base + (size_t)z * (size_t)(8192 * 512);
  const int row0 = blockIdx.y * 64, col0 = blockIdx.x * 128;
  f32x4 acc[2][4];
  gemm_core_512(A, WT, As, Bs, row0, col0, acc);
  const int lane = threadIdx.x & 63, wv = threadIdx.x >> 6;
  const int g = lane >> 4, r16 = lane & 15, wm = wv >> 1, wn = wv & 1;
#pragma unroll
  for (int n = 0; n < 4; ++n) {
    const int col = col0 + wn * 64 + n * 16 + r16;
    const float bn = bias[col];
#pragma unroll
    for (int m = 0; m < 2; ++m) {
      const int rowb = row0 + wm * 32 + m * 16 + g * 4;
#pragma unroll
      for (int r = 0; r < 4; ++r)
        C[(size_t)(rowb + r) * 512 + col] = __float2bfloat16(acc[m][n][r] + bn);
    }
  }
}

// Fused-weight GEMM: WfT[z] = (wo_z @ outw_z)^T, batched over z (bf16 out).
// A = outw^T slots, BT = wo (plain cast) slots, C = WfT slots; M = 512.
__global__ __launch_bounds__(256, 2)
void gemm_fusew_kernel(const __hip_bfloat16* __restrict__ A_base,
                       const __hip_bfloat16* __restrict__ BT_base,
                       __hip_bfloat16* __restrict__ C_base) {
  __shared__ __attribute__((aligned(16))) __hip_bfloat16 As[2048];
  __shared__ __attribute__((aligned(16))) __hip_bfloat16 Bs[4096];
  const size_t MS = (size_t)512 * 512;
  const int z = blockIdx.z;
  const __hip_bfloat16* A = A_base + z * MS;
  const __hip_bfloat16* BT = BT_base + z * MS;
  __hip_bfloat16* C = C_base + z * MS;
  const int row0 = blockIdx.y * 64, col0 = blockIdx.x * 128;
  f32x4 acc[2][4];
  gemm_core_512(A, BT, As, Bs, row0, col0, acc);
  const int lane = threadIdx.x & 63, wv = threadIdx.x >> 6;
  const int g = lane >> 4, r16 = lane & 15, wm = wv >> 1, wn = wv & 1;
#pragma unroll
  for (int n = 0; n < 4; ++n) {
    const int col = col0 + wn * 64 + n * 16 + r16;
#pragma unroll
    for (int m = 0; m < 2; ++m) {
      const int rowb = row0 + wm * 32 + m * 16 + g * 4;
#pragma unroll
      for (int r = 0; r < 4; ++r)
        C[(size_t)(rowb + r) * 512 + col] = __float2bfloat16(acc[m][n][r]);
    }
  }
}

// Branch output GEMM into fp32 out. mode 1: out = acc + bias;
// mode 2: out += acc + (bias ? bias : 0).
__global__ __launch_bounds__(256, 2)
void gemm_out_kernel(const __hip_bfloat16* __restrict__ A,
                     const __hip_bfloat16* __restrict__ WT,
                     const float* __restrict__ bias,
                     float* __restrict__ Cf, int mode) {
  __shared__ __attribute__((aligned(16))) __hip_bfloat16 As[2048];
  __shared__ __attribute__((aligned(16))) __hip_bfloat16 Bs[4096];
  const int row0 = blockIdx.y * 64, col0 = blockIdx.x * 128;
  f32x4 acc[2][4];
  gemm_core_512(A, WT, As, Bs, row0, col0, acc);
  const int lane = threadIdx.x & 63, wv = threadIdx.x >> 6;
  const int g = lane >> 4, r16 = lane & 15, wm = wv >> 1, wn = wv & 1;
#pragma unroll
  for (int n = 0; n < 4; ++n) {
    const int col = col0 + wn * 64 + n * 16 + r16;
    const float bn = bias ? bias[col] : 0.f;
#pragma unroll
    for (int m = 0; m < 2; ++m) {
      const int rowb = row0 + wm * 32 + m * 16 + g * 4;
#pragma unroll
      for (int r = 0; r < 4; ++r) {
        const size_t idx = (size_t)(rowb + r) * 512 + col;
        if (mode == 1) Cf[idx] = acc[m][n][r] + bn;
        else Cf[idx] += acc[m][n][r] + bn;
      }
    }
  }
}

// =====================================================================
// Local windowed attention (bf16 in/out), one wave per (b,t).
// Head split m = j*8+c = h*W+p; out-of-range rows == bias (fp32).
// att staging in LDS packed as bf16 pairs, stride 34 dwords:
// halves LDS (60.9 -> 30.5 KB) to lift the occupancy cap (2 -> 4 blk/CU).
// =====================================================================
template <int W>
__global__ __launch_bounds__(256)
void local_attn_kernel(const __hip_bfloat16* __restrict__ Xq,
                       const __hip_bfloat16* __restrict__ Xk,
                       const __hip_bfloat16* __restrict__ Xv,
                       const float* __restrict__ bq, const float* __restrict__ bk,
                       const float* __restrict__ bv,
                       __hip_bfloat16* __restrict__ abar) {
  constexpr int PAD = (W - 1) / 2;
  __shared__ unsigned att_lds[4][8 * W][34];
  const int wave = threadIdx.x >> 6;
  const int lane = threadIdx.x & 63;
  const int bt = (blockIdx.x << 2) + wave;
  const int b = bt >> 10, t = bt & 1023;
  const int h = lane >> 3;
  const int colb = (lane & 7) * 8;

  float q[W][8];
#pragma unroll
  for (int p = 0; p < W; ++p) {
    const int m = h * W + p, j = m >> 3, c = m & 7;
    const int s = t + j - PAD;
    if (s >= 0 && s < T_SEQ) {
      const u16x8 v = *(const u16x8*)(Xq + ((size_t)(b * T_SEQ + s) << 9) + c * 64 + colb);
#pragma unroll
      for (int e = 0; e < 8; ++e) q[p][e] = bf2f(v[e]);
    } else {
      const float* src = bq + c * 64 + colb;
      const float4 v0 = *(const float4*)src, v1 = *(const float4*)(src + 4);
      q[p][0] = v0.x; q[p][1] = v0.y; q[p][2] = v0.z; q[p][3] = v0.w;
      q[p][4] = v1.x; q[p][5] = v1.y; q[p][6] = v1.z; q[p][7] = v1.w;
    }
  }

  float sc[W][W];
#pragma unroll
  for (int pk = 0; pk < W; ++pk) {
    const int m = h * W + pk, j = m >> 3, c = m & 7;
    const int s = t + j - PAD;
    float kr[8];
    if (s >= 0 && s < T_SEQ) {
      const u16x8 v = *(const u16x8*)(Xk + ((size_t)(b * T_SEQ + s) << 9) + c * 64 + colb);
#pragma unroll
      for (int e = 0; e < 8; ++e) kr[e] = bf2f(v[e]);
    } else {
      const float* src = bk + c * 64 + colb;
      const float4 v0 = *(const float4*)src, v1 = *(const float4*)(src + 4);
      kr[0] = v0.x; kr[1] = v0.y; kr[2] = v0.z; kr[3] = v0.w;
      kr[4] = v1.x; kr[5] = v1.y; kr[6] = v1.z; kr[7] = v1.w;
    }
#pragma unroll
    for (int pq = 0; pq < W; ++pq) {
      float d = 0.f;
#pragma unroll
      for (int e = 0; e < 8; ++e) d = fmaf(q[pq][e], kr[e], d);
      d += __shfl_xor(d, 1);
      d += __shfl_xor(d, 2);
      d += __shfl_xor(d, 4);
      sc[pq][pk] = d * 0.125f;
    }
  }

#pragma unroll
  for (int pq = 0; pq < W; ++pq) {
    float mx = sc[pq][0];
#pragma unroll
    for (int pk = 1; pk < W; ++pk) mx = fmaxf(mx, sc[pq][pk]);
    float sum = 0.f;
#pragma unroll
    for (int pk = 0; pk < W; ++pk) {
      const float e = __expf(sc[pq][pk] - mx);
      sc[pq][pk] = e;
      sum += e;
    }
    const float inv = 1.f / sum;
#pragma unroll
    for (int pk = 0; pk < W; ++pk) sc[pq][pk] *= inv;
  }

  float av[W][8];
#pragma unroll
  for (int p = 0; p < W; ++p)
#pragma unroll
    for (int e = 0; e < 8; ++e) av[p][e] = 0.f;
#pragma unroll
  for (int pk = 0; pk < W; ++pk) {
    const int m = h * W + pk, j = m >> 3, c = m & 7;
    const int s = t + j - PAD;
    float vr[8];
    if (s >= 0 && s < T_SEQ) {
      const u16x8 v = *(const u16x8*)(Xv + ((size_t)(b * T_SEQ + s) << 9) + c * 64 + colb);
#pragma unroll
      for (int e = 0; e < 8; ++e) vr[e] = bf2f(v[e]);
    } else {
      const float* src = bv + c * 64 + colb;
      const float4 v0 = *(const float4*)src, v1 = *(const float4*)(src + 4);
      vr[0] = v0.x; vr[1] = v0.y; vr[2] = v0.z; vr[3] = v0.w;
      vr[4] = v1.x; vr[5] = v1.y; vr[6] = v1.z; vr[7] = v1.w;
    }
#pragma unroll
    for (int pq = 0; pq < W; ++pq)
#pragma unroll
      for (int e = 0; e < 8; ++e) av[pq][e] = fmaf(sc[pq][pk], vr[e], av[pq][e]);
  }

  // pack att rows (bf16 pairs) into LDS, indexed by m = j*8+c
#pragma unroll
  for (int p = 0; p < W; ++p) {
    const int m = h * W + p;
    unsigned d0, d1, d2, d3;
    CVTPK(d0, av[p][0], av[p][1]); CVTPK(d1, av[p][2], av[p][3]);
    CVTPK(d2, av[p][4], av[p][5]); CVTPK(d3, av[p][6], av[p][7]);
    unsigned* row = &att_lds[wave][m][colb >> 1];
    uint2 w0; w0.x = d0; w0.y = d1;
    uint2 w1; w1.x = d2; w1.y = d3;
    *(uint2*)row = w0;
    *(uint2*)(row + 2) = w1;
  }
  __syncthreads();
  const int cc = lane >> 3, fb4 = (lane & 7) * 4;
  float o[8] = {0.f, 0.f, 0.f, 0.f, 0.f, 0.f, 0.f, 0.f};
#pragma unroll
  for (int j = 0; j < W; ++j) {
    const unsigned* row = &att_lds[wave][j * 8 + cc][fb4];
    const uint2 a0 = *(const uint2*)row;
    const uint2 a1 = *(const uint2*)(row + 2);
    o[0] += bf2f((unsigned short)(a0.x & 0xffff));
    o[1] += bf2f((unsigned short)(a0.x >> 16));
    o[2] += bf2f((unsigned short)(a0.y & 0xffff));
    o[3] += bf2f((unsigned short)(a0.y >> 16));
    o[4] += bf2f((unsigned short)(a1.x & 0xffff));
    o[5] += bf2f((unsigned short)(a1.x >> 16));
    o[6] += bf2f((unsigned short)(a1.y & 0xffff));
    o[7] += bf2f((unsigned short)(a1.y >> 16));
  }
  const float invw = 1.f / (float)W;
  u16x8 ov;
#pragma unroll
  for (int e = 0; e < 8; ++e) ov[e] = f2bf(o[e] * invw);
  *(u16x8*)(abar + ((size_t)bt << 9) + lane * 8) = ov;
}

// =====================================================================
// Global attention, MFMA flash (32x32x16 bf16, swapped operands).
// (unchanged from round 3 — already < 68 us)
// =====================================================================
__global__ __launch_bounds__(256)
void global_attn_mfma_kernel(const __hip_bfloat16* __restrict__ Xq,
                             const __hip_bfloat16* __restrict__ Xk,
                             const __hip_bfloat16* __restrict__ Xv,
                             __hip_bfloat16* __restrict__ att) {
  __shared__ unsigned vt[2][2048];
  const int tid = threadIdx.x;
  const int lane = tid & 63;
  const int wv = tid >> 6;
  const int qblk = blockIdx.x;
  const int bh = blockIdx.y;
  const size_t base = (size_t)bh << 16;
  const int c = lane & 31;
  const int g = lane >> 5;
  const int q0 = qblk * 128 + wv * 32;

  const __hip_bfloat16* Qp = Xq + base;
  const __hip_bfloat16* Kp = Xk + base;
  const __hip_bfloat16* Vp = Xv + base;

  bf16x8 qf[4];
#pragma unroll
  for (int s = 0; s < 4; ++s)
    qf[s] = *(const bf16x8*)(Qp + (size_t)(q0 + c) * 64 + s * 16 + g * 8);

  const int k2 = tid & 31, dblk = tid >> 5;

  bf16x8 kf[2][4];
  u16x8 v0, v1, v0n, v1n;

  v0 = *(const u16x8*)(Vp + (size_t)(2 * k2) * 64 + dblk * 8);
  v1 = *(const u16x8*)(Vp + (size_t)(2 * k2 + 1) * 64 + dblk * 8);
#pragma unroll
  for (int kb = 0; kb < 2; ++kb)
#pragma unroll
    for (int s = 0; s < 4; ++s)
      kf[kb][s] = *(const bf16x8*)(Kp + (size_t)(kb * 32 + c) * 64 + s * 16 + g * 8);

  f32x16 Oa = (f32x16)(0.0f), Ob = (f32x16)(0.0f);
  float m_run = -3e38f, l_run = 0.f;

  for (int kt = 0; kt < 16; ++kt) {
    unsigned* vb = &vt[kt & 1][0];
#pragma unroll
    for (int jj = 0; jj < 8; ++jj) {
      const int d = dblk * 8 + jj;
      const unsigned dw = (unsigned)v0[jj] | ((unsigned)v1[jj] << 16);
      const int byte = (d * 128 + k2 * 4) ^ ((d & 7) << 4);
      vb[byte >> 2] = dw;
    }
    if (kt < 15) {
      const __hip_bfloat16* vsrc = Vp + (size_t)((kt + 1) * 64 + 2 * k2) * 64 + dblk * 8;
      v0n = *(const u16x8*)vsrc;
      v1n = *(const u16x8*)(vsrc + 64);
    }
    __syncthreads();

    f32x16 sa = (f32x16)(0.0f), sb = (f32x16)(0.0f);
#pragma unroll
    for (int s = 0; s < 4; ++s)
      sa = __builtin_amdgcn_mfma_f32_32x32x16_bf16(kf[0][s], qf[s], sa, 0, 0, 0);
#pragma unroll
    for (int s = 0; s < 4; ++s)
      sb = __builtin_amdgcn_mfma_f32_32x32x16_bf16(kf[1][s], qf[s], sb, 0, 0, 0);

    if (kt < 15) {
#pragma unroll
      for (int kb = 0; kb < 2; ++kb)
#pragma unroll
        for (int s = 0; s < 4; ++s)
          kf[kb][s] = *(const bf16x8*)(Kp + (size_t)((kt + 1) * 64 + kb * 32 + c) * 64 +
                                       s * 16 + g * 8);
    }

    float mx = sa[0];
#pragma unroll
    for (int r = 1; r < 16; ++r) mx = fmaxf(mx, sa[r]);
#pragma unroll
    for (int r = 0; r < 16; ++r) mx = fmaxf(mx, sb[r]);
    mx = fmaxf(mx, __shfl_xor(mx, 32));
    const float m_new = fmaxf(m_run, mx * 0.125f);
    const float alpha = __expf(m_run - m_new);

    float p0[16], p1[16];
    float lsum = 0.f;
#pragma unroll
    for (int r = 0; r < 16; ++r) { p0[r] = __expf(fmaf(sa[r], 0.125f, -m_new)); lsum += p0[r]; }
#pragma unroll
    for (int r = 0; r < 16; ++r) { p1[r] = __expf(fmaf(sb[r], 0.125f, -m_new)); lsum += p1[r]; }
    lsum += __shfl_xor(lsum, 32);
    l_run = fmaf(l_run, alpha, lsum);
    m_run = m_new;
#pragma unroll
    for (int r = 0; r < 16; ++r) { Oa[r] *= alpha; Ob[r] *= alpha; }

    unsigned bw[2][2][4];
#define REDIST(pb, kb_)                                                  \
    {                                                                    \
      unsigned t0, t1, t2, t3, t4, t5, t6, t7;                           \
      CVTPK(t0, pb[0], pb[1]);   CVTPK(t1, pb[2], pb[3]);                \
      CVTPK(t2, pb[4], pb[5]);   CVTPK(t3, pb[6], pb[7]);                \
      CVTPK(t4, pb[8], pb[9]);   CVTPK(t5, pb[10], pb[11]);              \
      CVTPK(t6, pb[12], pb[13]); CVTPK(t7, pb[14], pb[15]);              \
      swap32(t0, t2, lane); swap32(t1, t3, lane);                        \
      swap32(t4, t6, lane); swap32(t5, t7, lane);                        \
      bw[kb_][0][0] = t0; bw[kb_][0][1] = t1; bw[kb_][0][2] = t2;        \
      bw[kb_][0][3] = t3;                                                \
      bw[kb_][1][0] = t4; bw[kb_][1][1] = t5; bw[kb_][1][2] = t6;        \
      bw[kb_][1][3] = t7;                                                \
    }
    REDIST(p0, 0)
    REDIST(p1, 1)
#undef REDIST

    const unsigned* vbr = &vt[kt & 1][0];
#pragma unroll
    for (int kb = 0; kb < 2; ++kb)
#pragma unroll
      for (int st = 0; st < 2; ++st) {
        const u32x4 pw = { bw[kb][st][0], bw[kb][st][1], bw[kb][st][2], bw[kb][st][3] };
        const bf16x8 pf = __builtin_bit_cast(bf16x8, pw);
        {
          const int row = c;
          const int off = (row * 128 + (kb * 64 + st * 32 + g * 16)) ^ ((row & 7) << 4);
          const bf16x8 va = __builtin_bit_cast(bf16x8, *(const u32x4*)((const char*)vbr + off));
          Oa = __builtin_amdgcn_mfma_f32_32x32x16_bf16(va, pf, Oa, 0, 0, 0);
        }
        {
          const int row = 32 + c;
          const int off = (row * 128 + (kb * 64 + st * 32 + g * 16)) ^ ((row & 7) << 4);
          const bf16x8 va = __builtin_bit_cast(bf16x8, *(const u32x4*)((const char*)vbr + off));
          Ob = __builtin_amdgcn_mfma_f32_32x32x16_bf16(va, pf, Ob, 0, 0, 0);
        }
      }

    v0 = v0n; v1 = v1n;
  }

  const float inv = 1.f / l_run;
  __hip_bfloat16* drow = att + base + (size_t)(q0 + c) * 64;
#pragma unroll
  for (int qd = 0; qd < 4; ++qd) {
    unsigned lo, hi;
    {
      const float a0 = Oa[4 * qd + 0] * inv, a1 = Oa[4 * qd + 1] * inv;
      const float a2 = Oa[4 * qd + 2] * inv, a3 = Oa[4 * qd + 3] * inv;
      CVTPK(lo, a0, a1); CVTPK(hi, a2, a3);
      uint2 w; w.x = lo; w.y = hi;
      *(uint2*)(drow + 8 * qd + 4 * g) = w;
    }
    {
      const float a0 = Ob[4 * qd + 0] * inv, a1 = Ob[4 * qd + 1] * inv;
      const float a2 = Ob[4 * qd + 2] * inv, a3 = Ob[4 * qd + 3] * inv;
      CVTPK(lo, a0, a1); CVTPK(hi, a2, a3);
      uint2 w; w.x = lo; w.y = hi;
      *(uint2*)(drow + 32 + 8 * qd + 4 * g) = w;
    }
  }
}

// =====================================================================
// Launch
// =====================================================================
extern "C" void kernel_launch(void* const* d_in, const int* in_sizes, int n_in,
                              void* d_out, int out_size, void* d_ws, size_t ws_size,
                              hipStream_t stream) {
  const float* x      = (const float*)d_in[0];
  const float* loc_wq = (const float*)d_in[1];
  const float* loc_bq = (const float*)d_in[2];
  const float* loc_wk = (const float*)d_in[3];
  const float* loc_bk = (const float*)d_in[4];
  const float* loc_wv = (const float*)d_in[5];
  const float* loc_bv = (const float*)d_in[6];
  const float* loc_wo = (const float*)d_in[7];
  const float* loc_bo = (const float*)d_in[8];
  const float* g_wq  = (const float*)d_in[9];
  const float* g_bq  = (const float*)d_in[10];
  const float* g_wk  = (const float*)d_in[11];
  const float* g_bk  = (const float*)d_in[12];
  const float* g_wv  = (const float*)d_in[13];
  const float* g_bv  = (const float*)d_in[14];
  const float* g_wo  = (const float*)d_in[15];
  const float* g_bo  = (const float*)d_in[16];
  const float* out_w = (const float*)d_in[17];
  const float* out_b = (const float*)d_in[18];
  float* out = (float*)d_out;

  __hip_bfloat16* wsb = (__hip_bfloat16*)d_ws;
  const size_t SZ = (size_t)8192 * 512;
  const size_t MS = (size_t)512 * 512;
  // WT slots: 0-8 loc qkv (q0,q1,q2,k0..,v0..), 9-11 g qkv,
  //           12-15 outw^T, 16-19 wo (plain cast), 20-23 Wfused^T
  __hip_bfloat16* xb    = wsb;
  __hip_bfloat16* WT    = wsb + SZ;
  __hip_bfloat16* Xq    = wsb + SZ + 24 * MS;
  __hip_bfloat16* Xk    = Xq + SZ;
  __hip_bfloat16* Xv    = Xq + 2 * SZ;
  __hip_bfloat16* abar  = Xq + 3 * SZ;
  float* bfused = (float*)(Xq + 4 * SZ);   // 4 x 512 fp32

  const dim3 thr(256);

  // ---- one-time prep ----
  cast_x_kernel<<<2048, thr, 0, stream>>>(x, xb);
  transpose_cast_kernel<<<dim3(256, 3), thr, 0, stream>>>(loc_wq, WT + 0 * MS);
  transpose_cast_kernel<<<dim3(256, 3), thr, 0, stream>>>(loc_wk, WT + 3 * MS);
  transpose_cast_kernel<<<dim3(256, 3), thr, 0, stream>>>(loc_wv, WT + 6 * MS);
  transpose_cast_kernel<<<dim3(256, 1), thr, 0, stream>>>(g_wq, WT + 9 * MS);
  transpose_cast_kernel<<<dim3(256, 1), thr, 0, stream>>>(g_wk, WT + 10 * MS);
  transpose_cast_kernel<<<dim3(256, 1), thr, 0, stream>>>(g_wv, WT + 11 * MS);
  transpose_cast_kernel<<<dim3(256, 4), thr, 0, stream>>>(out_w, WT + 12 * MS);
  cast_x_kernel<<<384, thr, 0, stream>>>(loc_wo, (__hip_bfloat16*)(WT + 16 * MS));
  cast_x_kernel<<<128, thr, 0, stream>>>(g_wo, (__hip_bfloat16*)(WT + 19 * MS));
  // Wfused^T[z] = (wo_z @ outw_z)^T via A=outw^T, BT=wo
  gemm_fusew_kernel<<<dim3(4, 8, 4), thr, 0, stream>>>(WT + 12 * MS, WT + 16 * MS,
                                                       WT + 20 * MS);
  bias_fuse_kernel<<<dim3(2, 4), thr, 0, stream>>>(loc_bo, g_bo, out_w, out_b, bfused);

  const dim3 ggrid(4, 128);
  const dim3 gqkv(4, 128, 3);

  for (int lv = 0; lv < 3; ++lv) {
    gemm_qkv_kernel<<<gqkv, thr, 0, stream>>>(
        xb, WT + lv * MS, 3 * MS,
        loc_bq + lv * 512, loc_bk + lv * 512, loc_bv + lv * 512, Xq);

    if (lv == 0)
      local_attn_kernel<3><<<2048, thr, 0, stream>>>(
          Xq, Xk, Xv, loc_bq + lv * 512, loc_bk + lv * 512, loc_bv + lv * 512, abar);
    else if (lv == 1)
      local_attn_kernel<5><<<2048, thr, 0, stream>>>(
          Xq, Xk, Xv, loc_bq + lv * 512, loc_bk + lv * 512, loc_bv + lv * 512, abar);
    else
      local_attn_kernel<7><<<2048, thr, 0, stream>>>(
          Xq, Xk, Xv, loc_bq + lv * 512, loc_bk + lv * 512, loc_bv + lv * 512, abar);

    // out (+)= abar @ Wfused_lv + bfused_lv   (lv0 initializes)
    gemm_out_kernel<<<ggrid, thr, 0, stream>>>(abar, WT + (20 + lv) * MS,
                                               bfused + lv * 512, out, lv == 0 ? 1 : 2);
  }

  // global branch
  gemm_qkv_kernel<<<gqkv, thr, 0, stream>>>(xb, WT + 9 * MS, MS, g_bq, g_bk, g_bv, Xq);
  global_attn_mfma_kernel<<<dim3(8, 64), thr, 0, stream>>>(Xq, Xk, Xv, abar);
  gemm_out_kernel<<<ggrid, thr, 0, stream>>>(abar, WT + 23 * MS, bfused + 3 * 512, out, 2);
}

// Round 5
// 328.569 us; speedup vs baseline: 6.2972x; 1.1012x over previous
//
#include <hip/hip_runtime.h>
#include <hip/hip_bf16.h>
#include <cstddef>

#define T_SEQ 1024
#define D_MODEL 512

typedef __attribute__((ext_vector_type(8))) __bf16 bf16x8;
typedef __attribute__((ext_vector_type(4))) float f32x4;
typedef __attribute__((ext_vector_type(16))) float f32x16;
typedef __attribute__((ext_vector_type(8))) unsigned short u16x8;
typedef __attribute__((ext_vector_type(4))) unsigned int u32x4;

typedef const unsigned int __attribute__((address_space(1)))* gas1_t;
typedef unsigned int __attribute__((address_space(3)))* las3_t;

__device__ __forceinline__ void gload_lds16(const void* g, void* l) {
  __builtin_amdgcn_global_load_lds((gas1_t)g, (las3_t)l, 16, 0, 0);
}

__device__ __forceinline__ float bf2f(unsigned short u) {
  return __uint_as_float(((unsigned)u) << 16);
}
__device__ __forceinline__ unsigned short f2bf(float f) {
  __hip_bfloat16 h = __float2bfloat16(f);
  return *(unsigned short*)&h;
}

#define CVTPK(dst, a, b) \
  asm("v_cvt_pk_bf16_f32 %0, %1, %2" : "=v"(dst) : "v"(a), "v"(b))

// exchange lane halves between two dwords (for global attn P redistribution)
__device__ __forceinline__ void swap32(unsigned& a, unsigned& b, int lane) {
  const unsigned ax = __shfl_xor(a, 32);
  const unsigned bx = __shfl_xor(b, 32);
  const bool lo = lane < 32;
  const unsigned na = lo ? a : bx;
  const unsigned nb = lo ? ax : b;
  a = na; b = nb;
}

// sum over 4 lanes of a quad via DPP (VALU-speed, no DS pipe)
__device__ __forceinline__ float quad_reduce_add(float x) {
  const int y1 = __builtin_amdgcn_update_dpp(
      0, __builtin_bit_cast(int, x), 0xB1 /*quad_perm [1,0,3,2]*/, 0xF, 0xF, true);
  const float x1 = x + __builtin_bit_cast(float, y1);
  const int y2 = __builtin_amdgcn_update_dpp(
      0, __builtin_bit_cast(int, x1), 0x4E /*quad_perm [2,3,0,1]*/, 0xF, 0xF, true);
  return x1 + __builtin_bit_cast(float, y2);
}

// =====================================================================
// Cast fp32 -> bf16 (each thread 8 elems)
// =====================================================================
__global__ __launch_bounds__(256)
void cast_x_kernel(const float* __restrict__ in, __hip_bfloat16* __restrict__ out) {
  const int i = (blockIdx.x * 256 + threadIdx.x) * 8;
  const float4 a = *(const float4*)(in + i);
  const float4 b = *(const float4*)(in + i + 4);
  u16x8 o;
  o[0] = f2bf(a.x); o[1] = f2bf(a.y); o[2] = f2bf(a.z); o[3] = f2bf(a.w);
  o[4] = f2bf(b.x); o[5] = f2bf(b.y); o[6] = f2bf(b.z); o[7] = f2bf(b.w);
  *(u16x8*)(out + i) = o;
}

// =====================================================================
// Transpose+cast 512x512 fp32 matrices to bf16: dst[n][k] = src[k][n].
// =====================================================================
__global__ __launch_bounds__(256)
void transpose_cast_kernel(const float* __restrict__ src, __hip_bfloat16* __restrict__ dst) {
  __shared__ float tile[32][33];
  const float* W = src + (size_t)blockIdx.y * 262144;
  __hip_bfloat16* WT = dst + (size_t)blockIdx.y * 262144;
  const int tk = (blockIdx.x & 15) * 32;
  const int tn = (blockIdx.x >> 4) * 32;
  const int t = threadIdx.x;
  const int r = t >> 3, c4 = (t & 7) * 4;
  const float4 v = *(const float4*)(W + (size_t)(tk + r) * 512 + tn + c4);
  tile[r][c4 + 0] = v.x; tile[r][c4 + 1] = v.y;
  tile[r][c4 + 2] = v.z; tile[r][c4 + 3] = v.w;
  __syncthreads();
  ushort4 o;
  o.x = f2bf(tile[c4 + 0][r]); o.y = f2bf(tile[c4 + 1][r]);
  o.z = f2bf(tile[c4 + 2][r]); o.w = f2bf(tile[c4 + 3][r]);
  *(ushort4*)(WT + (size_t)(tn + r) * 512 + tk + c4) = o;
}

// =====================================================================
// Fused bias: bfused[z][n] = bo_z @ out_w[z*512..] (+ out_b for z==0).
// =====================================================================
__global__ __launch_bounds__(256)
void bias_fuse_kernel(const float* __restrict__ loc_bo, const float* __restrict__ g_bo,
                      const float* __restrict__ out_w, const float* __restrict__ out_b,
                      float* __restrict__ bfused) {
  const int z = blockIdx.y;
  const int n = blockIdx.x * 256 + threadIdx.x;
  const float* bo = (z < 3) ? loc_bo + z * 512 : g_bo;
  const float* W = out_w + (size_t)z * 512 * 512;
  float acc = (z == 0) ? out_b[n] : 0.f;
  for (int m = 0; m < 512; ++m)
    acc = fmaf(bo[m], W[(size_t)m * 512 + n], acc);
  bfused[z * 512 + n] = acc;
}

// =====================================================================
// MFMA GEMM core: BM=64 BN=128 BK=32. ACCUMULATES into acc (caller zeros).
// =====================================================================
__device__ __forceinline__ void gemm_core_512(
    const __hip_bfloat16* __restrict__ A, const __hip_bfloat16* __restrict__ BT,
    __hip_bfloat16* As, __hip_bfloat16* Bs, int row0, int col0, f32x4 acc[2][4]) {
  const int tid = threadIdx.x;
  const int wv = tid >> 6, lane = tid & 63;
  const int g = lane >> 4, r16 = lane & 15;
  const int wm = wv >> 1, wn = wv & 1;
  const char* Ab = (const char*)A;
  const char* Bb = (const char*)BT;
  for (int k0 = 0; k0 < 512; k0 += 32) {
    {
      const int row = tid >> 2, off = (tid & 3) << 4;
      gload_lds16(Ab + (size_t)(row0 + row) * 1024 + k0 * 2 + off,
                  (char*)As + (wv << 10));
    }
    {
      const int row = tid >> 2, off = (tid & 3) << 4;
      gload_lds16(Bb + (size_t)(col0 + row) * 1024 + k0 * 2 + off,
                  (char*)Bs + (wv << 10));
      const int c2 = tid + 256;
      const int row2 = c2 >> 2, off2 = (c2 & 3) << 4;
      gload_lds16(Bb + (size_t)(col0 + row2) * 1024 + k0 * 2 + off2,
                  (char*)Bs + 4096 + (wv << 10));
    }
    __syncthreads();
    bf16x8 a[2], b[4];
#pragma unroll
    for (int m = 0; m < 2; ++m)
      a[m] = *(const bf16x8*)(As + (wm * 32 + m * 16 + r16) * 32 + g * 8);
#pragma unroll
    for (int n = 0; n < 4; ++n)
      b[n] = *(const bf16x8*)(Bs + (wn * 64 + n * 16 + r16) * 32 + g * 8);
#pragma unroll
    for (int m = 0; m < 2; ++m)
#pragma unroll
      for (int n = 0; n < 4; ++n)
        acc[m][n] = __builtin_amdgcn_mfma_f32_16x16x32_bf16(a[m], b[n], acc[m][n], 0, 0, 0);
    __syncthreads();
  }
}

// Fused Q/K/V projection: blockIdx.z selects weight slot / bias / output.
__global__ __launch_bounds__(256, 2)
void gemm_qkv_kernel(const __hip_bfloat16* __restrict__ A,
                     const __hip_bfloat16* __restrict__ WT_base, size_t wt_stride,
                     const float* __restrict__ b0, const float* __restrict__ b1,
                     const float* __restrict__ b2,
                     __hip_bfloat16* __restrict__ out_base) {
  __shared__ __attribute__((aligned(16))) __hip_bfloat16 As[2048];
  __shared__ __attribute__((aligned(16))) __hip_bfloat16 Bs[4096];
  const int z = blockIdx.z;
  const __hip_bfloat16* WT = WT_base + (size_t)z * wt_stride;
  const float* bias = (z == 0) ? b0 : (z == 1) ? b1 : b2;
  __hip_bfloat16* C = out_base + (size_t)z * (size_t)(8192 * 512);
  const int row0 = blockIdx.y * 64, col0 = blockIdx.x * 128;
  f32x4 acc[2][4];
#pragma unroll
  for (int m = 0; m < 2; ++m)
#pragma unroll
    for (int n = 0; n < 4; ++n) acc[m][n] = (f32x4)(0.0f);
  gemm_core_512(A, WT, As, Bs, row0, col0, acc);
  const int lane = threadIdx.x & 63, wv = threadIdx.x >> 6;
  const int g = lane >> 4, r16 = lane & 15, wm = wv >> 1, wn = wv & 1;
#pragma unroll
  for (int n = 0; n < 4; ++n) {
    const int col = col0 + wn * 64 + n * 16 + r16;
    const float bn = bias[col];
#pragma unroll
    for (int m = 0; m < 2; ++m) {
      const int rowb = row0 + wm * 32 + m * 16 + g * 4;
#pragma unroll
      for (int r = 0; r < 4; ++r)
        C[(size_t)(rowb + r) * 512 + col] = __float2bfloat16(acc[m][n][r] + bn);
    }
  }
}

// Fused-weight GEMM: WfT[z] = (wo_z @ outw_z)^T, batched over z (bf16 out).
__global__ __launch_bounds__(256, 2)
void gemm_fusew_kernel(const __hip_bfloat16* __restrict__ A_base,
                       const __hip_bfloat16* __restrict__ BT_base,
                       __hip_bfloat16* __restrict__ C_base) {
  __shared__ __attribute__((aligned(16))) __hip_bfloat16 As[2048];
  __shared__ __attribute__((aligned(16))) __hip_bfloat16 Bs[4096];
  const size_t MS = (size_t)512 * 512;
  const int z = blockIdx.z;
  const __hip_bfloat16* A = A_base + z * MS;
  const __hip_bfloat16* BT = BT_base + z * MS;
  __hip_bfloat16* C = C_base + z * MS;
  const int row0 = blockIdx.y * 64, col0 = blockIdx.x * 128;
  f32x4 acc[2][4];
#pragma unroll
  for (int m = 0; m < 2; ++m)
#pragma unroll
    for (int n = 0; n < 4; ++n) acc[m][n] = (f32x4)(0.0f);
  gemm_core_512(A, BT, As, Bs, row0, col0, acc);
  const int lane = threadIdx.x & 63, wv = threadIdx.x >> 6;
  const int g = lane >> 4, r16 = lane & 15, wm = wv >> 1, wn = wv & 1;
#pragma unroll
  for (int n = 0; n < 4; ++n) {
    const int col = col0 + wn * 64 + n * 16 + r16;
#pragma unroll
    for (int m = 0; m < 2; ++m) {
      const int rowb = row0 + wm * 32 + m * 16 + g * 4;
#pragma unroll
      for (int r = 0; r < 4; ++r)
        C[(size_t)(rowb + r) * 512 + col] = __float2bfloat16(acc[m][n][r]);
    }
  }
}

// Final fused output GEMM: out = sum_z abar_z @ Wf_z + sum_z bfused_z.
// One dispatch, K=2048 in-register accumulation; out written exactly once.
__global__ __launch_bounds__(256, 2)
void gemm_out_fused_kernel(const __hip_bfloat16* __restrict__ A0,
                           const __hip_bfloat16* __restrict__ A1,
                           const __hip_bfloat16* __restrict__ A2,
                           const __hip_bfloat16* __restrict__ A3,
                           const __hip_bfloat16* __restrict__ WT_base,
                           const float* __restrict__ bfused,
                           float* __restrict__ out) {
  __shared__ __attribute__((aligned(16))) __hip_bfloat16 As[2048];
  __shared__ __attribute__((aligned(16))) __hip_bfloat16 Bs[4096];
  const size_t MS = (size_t)512 * 512;
  const int row0 = blockIdx.y * 64, col0 = blockIdx.x * 128;
  f32x4 acc[2][4];
#pragma unroll
  for (int m = 0; m < 2; ++m)
#pragma unroll
    for (int n = 0; n < 4; ++n) acc[m][n] = (f32x4)(0.0f);
  const __hip_bfloat16* Az[4] = {A0, A1, A2, A3};
  for (int z = 0; z < 4; ++z)
    gemm_core_512(Az[z], WT_base + (size_t)z * MS, As, Bs, row0, col0, acc);
  const int lane = threadIdx.x & 63, wv = threadIdx.x >> 6;
  const int g = lane >> 4, r16 = lane & 15, wm = wv >> 1, wn = wv & 1;
#pragma unroll
  for (int n = 0; n < 4; ++n) {
    const int col = col0 + wn * 64 + n * 16 + r16;
    const float bn = bfused[col] + bfused[512 + col] + bfused[1024 + col] +
                     bfused[1536 + col];
#pragma unroll
    for (int m = 0; m < 2; ++m) {
      const int rowb = row0 + wm * 32 + m * 16 + g * 4;
#pragma unroll
      for (int r = 0; r < 4; ++r)
        out[(size_t)(rowb + r) * 512 + col] = acc[m][n][r] + bn;
    }
  }
}

// =====================================================================
// Local windowed attention v3: latency-restructured.
// Block = 8 consecutive t of one b; K/V rows staged ONCE in LDS
// (bf16, XOR-swizzled (fb^c) -> conflict-free strided reads since the
// c-chunks are distinct across the 8 head groups for odd W).
// Wave handles 2 t's. Per t: K/V rows -> f32 regs (LDS-fast), streamed
// per-q-row softmax (no sc[W][W]), dot-reduce = 2 DPP quad adds + 1
// swizzle (DS-pipe ops 147 -> 49 per t), j-mean via one bijective
// ds_permute push per row (no LDS round-trip, no barrier).
// =====================================================================
template <int W>
__global__ __launch_bounds__(256)
void local_attn_kernel(const __hip_bfloat16* __restrict__ Xq,
                       const __hip_bfloat16* __restrict__ Xk,
                       const __hip_bfloat16* __restrict__ Xv,
                       const float* __restrict__ bq, const float* __restrict__ bk,
                       const float* __restrict__ bv,
                       __hip_bfloat16* __restrict__ abar) {
  constexpr int PAD = (W - 1) / 2;
  constexpr int TB = 8;
  constexpr int ROWS = TB + W - 1;
  __shared__ __attribute__((aligned(16))) char kl[ROWS * 1024];
  __shared__ __attribute__((aligned(16))) char vl[ROWS * 1024];
  const int tid = threadIdx.x;
  const int b = blockIdx.x >> 7;
  const int t0 = (blockIdx.x & 127) * TB;

  // ---- stage K,V rows [t0-PAD, t0+TB-1+PAD] into swizzled LDS ----
  constexpr int NCH = ROWS * 64;              // 16B chunks per tensor
  constexpr int ITERS = (2 * NCH + 255) / 256;
#pragma unroll
  for (int it = 0; it < ITERS; ++it) {
    const int idx = tid + it * 256;
    if (idx < 2 * NCH) {
      const bool isK = idx < NCH;
      const int i2 = isK ? idx : idx - NCH;
      const int r = i2 >> 6, c = (i2 >> 3) & 7, fw = i2 & 7;
      const int s = t0 - PAD + r;
      u16x8 v;
      if (s >= 0 && s < T_SEQ) {
        const __hip_bfloat16* src = isK ? Xk : Xv;
        v = *(const u16x8*)(src + ((size_t)(b * T_SEQ + s) << 9) + c * 64 + fw * 8);
      } else {
        const float* bias = isK ? bk : bv;
#pragma unroll
        for (int e = 0; e < 8; ++e) v[e] = f2bf(bias[c * 64 + fw * 8 + e]);
      }
      char* dst = isK ? kl : vl;
      *(u16x8*)(dst + r * 1024 + c * 128 + ((fw ^ c) & 7) * 16) = v;
    }
  }
  __syncthreads();

  const int wv = tid >> 6, lane = tid & 63;
  const int h = lane >> 3, fb = lane & 7;
  const float invw = 1.f / (float)W;

#pragma unroll
  for (int tt = 0; tt < 2; ++tt) {
    const int t = t0 + wv * 2 + tt;

    // ---- q window (bf16, all loads issued upfront) ----
    u16x8 qw[W];
#pragma unroll
    for (int p = 0; p < W; ++p) {
      const int m = h * W + p, j = m >> 3, c = m & 7;
      const int s = t + j - PAD;
      if (s >= 0 && s < T_SEQ) {
        qw[p] = *(const u16x8*)(Xq + ((size_t)(b * T_SEQ + s) << 9) + c * 64 + fb * 8);
      } else {
#pragma unroll
        for (int e = 0; e < 8; ++e) qw[p][e] = f2bf(bq[c * 64 + fb * 8 + e]);
      }
    }

    // ---- K,V rows from LDS -> f32 regs (converted once per t) ----
    float kr[W][8], vr[W][8];
#pragma unroll
    for (int pk = 0; pk < W; ++pk) {
      const int m = h * W + pk, j = m >> 3, c = m & 7;
      const int off = (t - t0 + j) * 1024 + c * 128 + ((fb ^ c) & 7) * 16;
      const u16x8 kv = *(const u16x8*)(kl + off);
      const u16x8 vv = *(const u16x8*)(vl + off);
#pragma unroll
      for (int e = 0; e < 8; ++e) {
        kr[pk][e] = bf2f(kv[e]);
        vr[pk][e] = bf2f(vv[e]);
      }
    }

    float o[8] = {0.f, 0.f, 0.f, 0.f, 0.f, 0.f, 0.f, 0.f};
#pragma unroll
    for (int pq = 0; pq < W; ++pq) {
      float q8[8];
#pragma unroll
      for (int e = 0; e < 8; ++e) q8[e] = bf2f(qw[pq][e]);

      float s_[W];
#pragma unroll
      for (int pk = 0; pk < W; ++pk) {
        float d = 0.f;
#pragma unroll
        for (int e = 0; e < 8; ++e) d = fmaf(q8[e], kr[pk][e], d);
        d = quad_reduce_add(d);
        d += __shfl_xor(d, 4);
        s_[pk] = d * 0.125f;
      }

      float mx = s_[0];
#pragma unroll
      for (int pk = 1; pk < W; ++pk) mx = fmaxf(mx, s_[pk]);
      float sum = 0.f;
#pragma unroll
      for (int pk = 0; pk < W; ++pk) {
        s_[pk] = __expf(s_[pk] - mx);
        sum += s_[pk];
      }
      const float inv = 1.f / sum;

      float av[8] = {0.f, 0.f, 0.f, 0.f, 0.f, 0.f, 0.f, 0.f};
#pragma unroll
      for (int pk = 0; pk < W; ++pk) {
        const float p = s_[pk] * inv;
#pragma unroll
        for (int e = 0; e < 8; ++e) av[e] = fmaf(p, vr[pk][e], av[e]);
      }

      // push att row m to the lane that accumulates its j-mean slot
      unsigned d0, d1, d2, d3;
      CVTPK(d0, av[0], av[1]); CVTPK(d1, av[2], av[3]);
      CVTPK(d2, av[4], av[5]); CVTPK(d3, av[6], av[7]);
      const int m = h * W + pq;
      const int dl4 = (((m & 7) << 3) + fb) << 2;
      const int r0 = __builtin_amdgcn_ds_permute(dl4, (int)d0);
      const int r1 = __builtin_amdgcn_ds_permute(dl4, (int)d1);
      const int r2 = __builtin_amdgcn_ds_permute(dl4, (int)d2);
      const int r3 = __builtin_amdgcn_ds_permute(dl4, (int)d3);
      o[0] += bf2f((unsigned short)(r0 & 0xffff));
      o[1] += bf2f((unsigned short)((unsigned)r0 >> 16));
      o[2] += bf2f((unsigned short)(r1 & 0xffff));
      o[3] += bf2f((unsigned short)((unsigned)r1 >> 16));
      o[4] += bf2f((unsigned short)(r2 & 0xffff));
      o[5] += bf2f((unsigned short)((unsigned)r2 >> 16));
      o[6] += bf2f((unsigned short)(r3 & 0xffff));
      o[7] += bf2f((unsigned short)((unsigned)r3 >> 16));
    }

    u16x8 ov;
#pragma unroll
    for (int e = 0; e < 8; ++e) ov[e] = f2bf(o[e] * invw);
    *(u16x8*)(abar + ((size_t)(b * T_SEQ + t) << 9) + lane * 8) = ov;
  }
}

// =====================================================================
// Global attention, MFMA flash (32x32x16 bf16, swapped operands).
// (unchanged from round 3/4)
// =====================================================================
__global__ __launch_bounds__(256)
void global_attn_mfma_kernel(const __hip_bfloat16* __restrict__ Xq,
                             const __hip_bfloat16* __restrict__ Xk,
                             const __hip_bfloat16* __restrict__ Xv,
                             __hip_bfloat16* __restrict__ att) {
  __shared__ unsigned vt[2][2048];
  const int tid = threadIdx.x;
  const int lane = tid & 63;
  const int wv = tid >> 6;
  const int qblk = blockIdx.x;
  const int bh = blockIdx.y;
  const size_t base = (size_t)bh << 16;
  const int c = lane & 31;
  const int g = lane >> 5;
  const int q0 = qblk * 128 + wv * 32;

  const __hip_bfloat16* Qp = Xq + base;
  const __hip_bfloat16* Kp = Xk + base;
  const __hip_bfloat16* Vp = Xv + base;

  bf16x8 qf[4];
#pragma unroll
  for (int s = 0; s < 4; ++s)
    qf[s] = *(const bf16x8*)(Qp + (size_t)(q0 + c) * 64 + s * 16 + g * 8);

  const int k2 = tid & 31, dblk = tid >> 5;

  bf16x8 kf[2][4];
  u16x8 v0, v1, v0n, v1n;

  v0 = *(const u16x8*)(Vp + (size_t)(2 * k2) * 64 + dblk * 8);
  v1 = *(const u16x8*)(Vp + (size_t)(2 * k2 + 1) * 64 + dblk * 8);
#pragma unroll
  for (int kb = 0; kb < 2; ++kb)
#pragma unroll
    for (int s = 0; s < 4; ++s)
      kf[kb][s] = *(const bf16x8*)(Kp + (size_t)(kb * 32 + c) * 64 + s * 16 + g * 8);

  f32x16 Oa = (f32x16)(0.0f), Ob = (f32x16)(0.0f);
  float m_run = -3e38f, l_run = 0.f;

  for (int kt = 0; kt < 16; ++kt) {
    unsigned* vb = &vt[kt & 1][0];
#pragma unroll
    for (int jj = 0; jj < 8; ++jj) {
      const int d = dblk * 8 + jj;
      const unsigned dw = (unsigned)v0[jj] | ((unsigned)v1[jj] << 16);
      const int byte = (d * 128 + k2 * 4) ^ ((d & 7) << 4);
      vb[byte >> 2] = dw;
    }
    if (kt < 15) {
      const __hip_bfloat16* vsrc = Vp + (size_t)((kt + 1) * 64 + 2 * k2) * 64 + dblk * 8;
      v0n = *(const u16x8*)vsrc;
      v1n = *(const u16x8*)(vsrc + 64);
    }
    __syncthreads();

    f32x16 sa = (f32x16)(0.0f), sb = (f32x16)(0.0f);
#pragma unroll
    for (int s = 0; s < 4; ++s)
      sa = __builtin_amdgcn_mfma_f32_32x32x16_bf16(kf[0][s], qf[s], sa, 0, 0, 0);
#pragma unroll
    for (int s = 0; s < 4; ++s)
      sb = __builtin_amdgcn_mfma_f32_32x32x16_bf16(kf[1][s], qf[s], sb, 0, 0, 0);

    if (kt < 15) {
#pragma unroll
      for (int kb = 0; kb < 2; ++kb)
#pragma unroll
        for (int s = 0; s < 4; ++s)
          kf[kb][s] = *(const bf16x8*)(Kp + (size_t)((kt + 1) * 64 + kb * 32 + c) * 64 +
                                       s * 16 + g * 8);
    }

    float mx = sa[0];
#pragma unroll
    for (int r = 1; r < 16; ++r) mx = fmaxf(mx, sa[r]);
#pragma unroll
    for (int r = 0; r < 16; ++r) mx = fmaxf(mx, sb[r]);
    mx = fmaxf(mx, __shfl_xor(mx, 32));
    const float m_new = fmaxf(m_run, mx * 0.125f);
    const float alpha = __expf(m_run - m_new);

    float p0[16], p1[16];
    float lsum = 0.f;
#pragma unroll
    for (int r = 0; r < 16; ++r) { p0[r] = __expf(fmaf(sa[r], 0.125f, -m_new)); lsum += p0[r]; }
#pragma unroll
    for (int r = 0; r < 16; ++r) { p1[r] = __expf(fmaf(sb[r], 0.125f, -m_new)); lsum += p1[r]; }
    lsum += __shfl_xor(lsum, 32);
    l_run = fmaf(l_run, alpha, lsum);
    m_run = m_new;
#pragma unroll
    for (int r = 0; r < 16; ++r) { Oa[r] *= alpha; Ob[r] *= alpha; }

    unsigned bw[2][2][4];
#define REDIST(pb, kb_)                                                  \
    {                                                                    \
      unsigned t0_, t1_, t2_, t3_, t4_, t5_, t6_, t7_;                   \
      CVTPK(t0_, pb[0], pb[1]);   CVTPK(t1_, pb[2], pb[3]);              \
      CVTPK(t2_, pb[4], pb[5]);   CVTPK(t3_, pb[6], pb[7]);              \
      CVTPK(t4_, pb[8], pb[9]);   CVTPK(t5_, pb[10], pb[11]);            \
      CVTPK(t6_, pb[12], pb[13]); CVTPK(t7_, pb[14], pb[15]);            \
      swap32(t0_, t2_, lane); swap32(t1_, t3_, lane);                    \
      swap32(t4_, t6_, lane); swap32(t5_, t7_, lane);                    \
      bw[kb_][0][0] = t0_; bw[kb_][0][1] = t1_; bw[kb_][0][2] = t2_;     \
      bw[kb_][0][3] = t3_;                                               \
      bw[kb_][1][0] = t4_; bw[kb_][1][1] = t5_; bw[kb_][1][2] = t6_;     \
      bw[kb_][1][3] = t7_;                                               \
    }
    REDIST(p0, 0)
    REDIST(p1, 1)
#undef REDIST

    const unsigned* vbr = &vt[kt & 1][0];
#pragma unroll
    for (int kb = 0; kb < 2; ++kb)
#pragma unroll
      for (int st = 0; st < 2; ++st) {
        const u32x4 pw = { bw[kb][st][0], bw[kb][st][1], bw[kb][st][2], bw[kb][st][3] };
        const bf16x8 pf = __builtin_bit_cast(bf16x8, pw);
        {
          const int row = c;
          const int off = (row * 128 + (kb * 64 + st * 32 + g * 16)) ^ ((row & 7) << 4);
          const bf16x8 va = __builtin_bit_cast(bf16x8, *(const u32x4*)((const char*)vbr + off));
          Oa = __builtin_amdgcn_mfma_f32_32x32x16_bf16(va, pf, Oa, 0, 0, 0);
        }
        {
          const int row = 32 + c;
          const int off = (row * 128 + (kb * 64 + st * 32 + g * 16)) ^ ((row & 7) << 4);
          const bf16x8 va = __builtin_bit_cast(bf16x8, *(const u32x4*)((const char*)vbr + off));
          Ob = __builtin_amdgcn_mfma_f32_32x32x16_bf16(va, pf, Ob, 0, 0, 0);
        }
      }

    v0 = v0n; v1 = v1n;
  }

  const float inv = 1.f / l_run;
  __hip_bfloat16* drow = att + base + (size_t)(q0 + c) * 64;
#pragma unroll
  for (int qd = 0; qd < 4; ++qd) {
    unsigned lo, hi;
    {
      const float a0 = Oa[4 * qd + 0] * inv, a1 = Oa[4 * qd + 1] * inv;
      const float a2 = Oa[4 * qd + 2] * inv, a3 = Oa[4 * qd + 3] * inv;
      CVTPK(lo, a0, a1); CVTPK(hi, a2, a3);
      uint2 w; w.x = lo; w.y = hi;
      *(uint2*)(drow + 8 * qd + 4 * g) = w;
    }
    {
      const float a0 = Ob[4 * qd + 0] * inv, a1 = Ob[4 * qd + 1] * inv;
      const float a2 = Ob[4 * qd + 2] * inv, a3 = Ob[4 * qd + 3] * inv;
      CVTPK(lo, a0, a1); CVTPK(hi, a2, a3);
      uint2 w; w.x = lo; w.y = hi;
      *(uint2*)(drow + 32 + 8 * qd + 4 * g) = w;
    }
  }
}

// =====================================================================
// Launch
// =====================================================================
extern "C" void kernel_launch(void* const* d_in, const int* in_sizes, int n_in,
                              void* d_out, int out_size, void* d_ws, size_t ws_size,
                              hipStream_t stream) {
  const float* x      = (const float*)d_in[0];
  const float* loc_wq = (const float*)d_in[1];
  const float* loc_bq = (const float*)d_in[2];
  const float* loc_wk = (const float*)d_in[3];
  const float* loc_bk = (const float*)d_in[4];
  const float* loc_wv = (const float*)d_in[5];
  const float* loc_bv = (const float*)d_in[6];
  const float* loc_wo = (const float*)d_in[7];
  const float* loc_bo = (const float*)d_in[8];
  const float* g_wq  = (const float*)d_in[9];
  const float* g_bq  = (const float*)d_in[10];
  const float* g_wk  = (const float*)d_in[11];
  const float* g_bk  = (const float*)d_in[12];
  const float* g_wv  = (const float*)d_in[13];
  const float* g_bv  = (const float*)d_in[14];
  const float* g_wo  = (const float*)d_in[15];
  const float* g_bo  = (const float*)d_in[16];
  const float* out_w = (const float*)d_in[17];
  const float* out_b = (const float*)d_in[18];
  float* out = (float*)d_out;

  __hip_bfloat16* wsb = (__hip_bfloat16*)d_ws;
  const size_t SZ = (size_t)8192 * 512;
  const size_t MS = (size_t)512 * 512;
  // WT slots: 0-8 loc qkv, 9-11 g qkv, 12-15 outw^T, 16-19 wo (plain),
  //           20-23 Wfused^T
  __hip_bfloat16* xb    = wsb;
  __hip_bfloat16* WT    = wsb + SZ;
  __hip_bfloat16* Xq    = wsb + SZ + 24 * MS;
  __hip_bfloat16* Xk    = Xq + SZ;
  __hip_bfloat16* Xv    = Xq + 2 * SZ;
  __hip_bfloat16* abar0 = Xq + 3 * SZ;
  __hip_bfloat16* abar1 = Xq + 4 * SZ;
  __hip_bfloat16* abar2 = Xq + 5 * SZ;
  __hip_bfloat16* abar3 = Xq + 6 * SZ;
  float* bfused = (float*)(Xq + 7 * SZ);   // 4 x 512 fp32
  __hip_bfloat16* abars[3] = {abar0, abar1, abar2};

  const dim3 thr(256);

  // ---- one-time prep ----
  cast_x_kernel<<<2048, thr, 0, stream>>>(x, xb);
  transpose_cast_kernel<<<dim3(256, 3), thr, 0, stream>>>(loc_wq, WT + 0 * MS);
  transpose_cast_kernel<<<dim3(256, 3), thr, 0, stream>>>(loc_wk, WT + 3 * MS);
  transpose_cast_kernel<<<dim3(256, 3), thr, 0, stream>>>(loc_wv, WT + 6 * MS);
  transpose_cast_kernel<<<dim3(256, 1), thr, 0, stream>>>(g_wq, WT + 9 * MS);
  transpose_cast_kernel<<<dim3(256, 1), thr, 0, stream>>>(g_wk, WT + 10 * MS);
  transpose_cast_kernel<<<dim3(256, 1), thr, 0, stream>>>(g_wv, WT + 11 * MS);
  transpose_cast_kernel<<<dim3(256, 4), thr, 0, stream>>>(out_w, WT + 12 * MS);
  cast_x_kernel<<<384, thr, 0, stream>>>(loc_wo, (__hip_bfloat16*)(WT + 16 * MS));
  cast_x_kernel<<<128, thr, 0, stream>>>(g_wo, (__hip_bfloat16*)(WT + 19 * MS));
  gemm_fusew_kernel<<<dim3(4, 8, 4), thr, 0, stream>>>(WT + 12 * MS, WT + 16 * MS,
                                                       WT + 20 * MS);
  bias_fuse_kernel<<<dim3(2, 4), thr, 0, stream>>>(loc_bo, g_bo, out_w, out_b, bfused);

  const dim3 ggrid(4, 128);
  const dim3 gqkv(4, 128, 3);

  for (int lv = 0; lv < 3; ++lv) {
    gemm_qkv_kernel<<<gqkv, thr, 0, stream>>>(
        xb, WT + lv * MS, 3 * MS,
        loc_bq + lv * 512, loc_bk + lv * 512, loc_bv + lv * 512, Xq);

    if (lv == 0)
      local_attn_kernel<3><<<1024, thr, 0, stream>>>(
          Xq, Xk, Xv, loc_bq + lv * 512, loc_bk + lv * 512, loc_bv + lv * 512, abars[lv]);
    else if (lv == 1)
      local_attn_kernel<5><<<1024, thr, 0, stream>>>(
          Xq, Xk, Xv, loc_bq + lv * 512, loc_bk + lv * 512, loc_bv + lv * 512, abars[lv]);
    else
      local_attn_kernel<7><<<1024, thr, 0, stream>>>(
          Xq, Xk, Xv, loc_bq + lv * 512, loc_bk + lv * 512, loc_bv + lv * 512, abars[lv]);
  }

  // global branch
  gemm_qkv_kernel<<<gqkv, thr, 0, stream>>>(xb, WT + 9 * MS, MS, g_bq, g_bk, g_bv, Xq);
  global_attn_mfma_kernel<<<dim3(8, 64), thr, 0, stream>>>(Xq, Xk, Xv, abar3);

  // fused output projection: one K=2048 GEMM, out written once
  gemm_out_fused_kernel<<<ggrid, thr, 0, stream>>>(abar0, abar1, abar2, abar3,
                                                   WT + 20 * MS, bfused, out);
}